// Round 4
// baseline (4622.691 us; speedup 1.0000x reference)
//
#include <hip/hip_runtime.h>
#include <cstddef>
#include <cstdint>

// VQ-VAE segment, chunked pipeline. Round 4: dual-chain MFMA LSTM
// (2 independent 16-batch recurrences per 1024-thread block -> 4 waves/SIMD),
// conflict-free LDS h-buffer layout, cvt_pk bf16 packing.
// B=256 T=512 D=96 H=128 4H=512 L=128 K=1024.

#define B_ 256
#define T_ 512
#define D_ 96
#define H_ 128
#define G_ 512
#define L_ 128
#define K_ 1024

typedef __attribute__((ext_vector_type(8))) short bf16x8;
typedef __attribute__((ext_vector_type(4))) float f32x4;

__device__ __forceinline__ float fsig(float x) { return 1.0f / (1.0f + __expf(-x)); }
__device__ __forceinline__ float ftanh(float x) { return 1.0f - 2.0f / (1.0f + __expf(2.0f * x)); }

__device__ __forceinline__ ushort f2bf(float f) {
    union { float f; uint u; } v; v.f = f;
    uint u = v.u;
    return (ushort)((u + 0x7FFFu + ((u >> 16) & 1u)) >> 16);
}

__device__ __forceinline__ uint cvt_pk_bf16(float a, float b) {
    uint r;
    asm("v_cvt_pk_bf16_f32 %0, %1, %2" : "=v"(r) : "v"(a), "v"(b));
    return r;
}

__device__ __forceinline__ size_t rowOff(int m, int lg, long stride, int len) {
    return (size_t)(m >> lg) * (size_t)stride + (size_t)(m & ((1 << lg) - 1)) * (size_t)len;
}

__global__ __launch_bounds__(256) void zero_kernel(float* __restrict__ p, int n)
{
    int i = blockIdx.x * 256 + threadIdx.x;
    if (i < n) p[i] = 0.f;
}

// ---------------------------------------------------------------------------
// C[m,n] = dot(Arow(m), W[n]) + b0[n] (+b1[n]).  BM=BN=64, BK=32, block 256.
// ---------------------------------------------------------------------------
__global__ __launch_bounds__(256) void gemm_bias_kernel(
    const float* __restrict__ A, long aStride, int lgA,
    const float* __restrict__ W,
    const float* __restrict__ b0, const float* __restrict__ b1,
    float* __restrict__ C, long cStride, int lgC,
    int N, int K)
{
    __shared__ __align__(16) float As[32][68];
    __shared__ __align__(16) float Bs[32][68];
    const int n_base = blockIdx.x * 64, m_base = blockIdx.y * 64;
    const int tid = threadIdx.x;
    const int tx = tid & 15, ty = tid >> 4;

    float acc[4][4] = {};

    for (int k0 = 0; k0 < K; k0 += 32) {
#pragma unroll
        for (int r = 0; r < 2; ++r) {
            int f4 = tid + r * 256;
            int m = f4 >> 3;
            int kq = (f4 & 7) * 4;
            float4 v = *(const float4*)(A + rowOff(m_base + m, lgA, aStride, K) + (k0 + kq));
            As[kq + 0][m] = v.x; As[kq + 1][m] = v.y; As[kq + 2][m] = v.z; As[kq + 3][m] = v.w;
            float4 wv = make_float4(0.f, 0.f, 0.f, 0.f);
            if (n_base + m < N)
                wv = *(const float4*)(W + (size_t)(n_base + m) * K + (k0 + kq));
            Bs[kq + 0][m] = wv.x; Bs[kq + 1][m] = wv.y; Bs[kq + 2][m] = wv.z; Bs[kq + 3][m] = wv.w;
        }
        __syncthreads();
#pragma unroll
        for (int k = 0; k < 32; ++k) {
            float4 a4 = *(const float4*)&As[k][ty * 4];
            float4 b4 = *(const float4*)&Bs[k][tx * 4];
            float a_[4] = {a4.x, a4.y, a4.z, a4.w};
            float b_[4] = {b4.x, b4.y, b4.z, b4.w};
#pragma unroll
            for (int i = 0; i < 4; ++i)
#pragma unroll
                for (int j = 0; j < 4; ++j)
                    acc[i][j] = fmaf(a_[i], b_[j], acc[i][j]);
        }
        __syncthreads();
    }

#pragma unroll
    for (int i = 0; i < 4; ++i) {
        int m = m_base + ty * 4 + i;
        size_t cro = rowOff(m, lgC, cStride, N);
#pragma unroll
        for (int j = 0; j < 4; ++j) {
            int n = n_base + tx * 4 + j;
            if (n < N) {
                float bias = (b0 ? b0[n] : 0.f) + (b1 ? b1[n] : 0.f);
                C[cro + n] = acc[i][j] + bias;
            }
        }
    }
}

// ---------------------------------------------------------------------------
// Dual-chain MFMA LSTM. grid = B/32, block = 1024 (16 waves = 2 chains x 8).
// Chain handles 16 batches; wave w of a chain owns M-tiles {w,w+8,w+16,w+24}
// of G^T[512,16] = Whh_bf16 * H^T_bf16 (mfma_f32_16x16x32_bf16, C-in = preX).
// Lane l: colb=l&15 (batch), g=l>>4, h-rows hi0=16w+4g..+3.
// LDS h layout: block bk=h>>3 (16B = 8 bf16 per batch), slot = colb^(bk&7):
//   reads (fixed g => fixed bk) are contiguous permuted 256B rows (conflict-
//   free); writes are 8B halves, 2-way max (free).
// ---------------------------------------------------------------------------
__global__ __launch_bounds__(1024) void lstm_mfma_kernel(
    const float* __restrict__ preXc,    // [B][Tc][512] or nullptr
    const float* __restrict__ idxBase,  // idxf + t0 (row stride T_) or nullptr
    const float* __restrict__ preCB,    // [1024][512]
    const float* __restrict__ Whh,      // [512][128]
    float* __restrict__ Hc,             // [B][Tc][128]
    float* __restrict__ hstate,         // [B][128]
    float* __restrict__ cstate,         // [B][128]
    int Tc)
{
    __shared__ __align__(16) ushort hbuf[2][2][2048];  // [chain][dbuf][4KB]
    const int tid = threadIdx.x;
    const int wAll = tid >> 6;
    const int chain = wAll >> 3;
    const int w = wAll & 7;
    const int l = tid & 63;
    const int colb = l & 15;
    const int g = l >> 4;
    const int b = blockIdx.x * 32 + chain * 16 + colb;
    const int hi0 = 16 * w + 4 * g;

    // LDS byte offsets (computed once)
    const int bk_w = 2 * w + (g >> 1);
    const int wr_off = bk_w * 256 + ((colb ^ (bk_w & 7)) << 4) + ((g & 1) << 3);
    int rd_off[4];
#pragma unroll
    for (int kt = 0; kt < 4; ++kt) {
        int bk = 4 * kt + g;
        rd_off[kt] = bk * 256 + ((colb ^ (bk & 7)) << 4);
    }

    // Whh A-fragments -> bf16 registers (persist all steps)
    bf16x8 afrag[4][4];
#pragma unroll
    for (int q = 0; q < 4; ++q) {
        const float* wr = Whh + (size_t)(q * 128 + 16 * w + colb) * 128;
#pragma unroll
        for (int kt = 0; kt < 4; ++kt) {
            float4 x0 = *(const float4*)(wr + kt * 32 + g * 8);
            float4 x1 = *(const float4*)(wr + kt * 32 + g * 8 + 4);
            union { bf16x8 v; ushort u[8]; } o;
            o.u[0] = f2bf(x0.x); o.u[1] = f2bf(x0.y); o.u[2] = f2bf(x0.z); o.u[3] = f2bf(x0.w);
            o.u[4] = f2bf(x1.x); o.u[5] = f2bf(x1.y); o.u[6] = f2bf(x1.z); o.u[7] = f2bf(x1.w);
            afrag[q][kt] = o.v;
        }
    }

    float4 c = *(const float4*)(cstate + (size_t)b * H_ + hi0);
    float4 hlast = *(const float4*)(hstate + (size_t)b * H_ + hi0);
    {   // initial h -> hbuf[chain][0]
        uint2 p;
        p.x = cvt_pk_bf16(hlast.x, hlast.y);
        p.y = cvt_pk_bf16(hlast.z, hlast.w);
        *(uint2*)((char*)hbuf[chain][0] + wr_off) = p;
    }

    // prime prefetch for t=0
    float4 pre[4];
    {
        const float* p0;
        if (preXc) p0 = preXc + (size_t)b * Tc * G_;
        else {
            int k0 = (int)idxBase[(size_t)b * T_];
            p0 = preCB + (size_t)k0 * G_;
        }
#pragma unroll
        for (int q = 0; q < 4; ++q) pre[q] = *(const float4*)(p0 + q * 128 + hi0);
    }
    __syncthreads();

    int cur = 0;
#pragma unroll 2
    for (int t = 0; t < Tc; ++t) {
        // prefetch t+1 (hidden under this step's compute)
        float4 preN[4];
        if (t + 1 < Tc) {
            const float* pn;
            if (preXc) pn = preXc + ((size_t)b * Tc + t + 1) * G_;
            else {
                int kn = (int)idxBase[(size_t)b * T_ + t + 1];
                pn = preCB + (size_t)kn * G_;
            }
#pragma unroll
            for (int q = 0; q < 4; ++q) preN[q] = *(const float4*)(pn + q * 128 + hi0);
        }

        // B-fragments (conflict-free reads)
        bf16x8 bfrag[4];
#pragma unroll
        for (int kt = 0; kt < 4; ++kt)
            bfrag[kt] = *(const bf16x8*)((const char*)hbuf[chain][cur] + rd_off[kt]);

        f32x4 acc[4];
#pragma unroll
        for (int q = 0; q < 4; ++q) {
            acc[q][0] = pre[q].x; acc[q][1] = pre[q].y;
            acc[q][2] = pre[q].z; acc[q][3] = pre[q].w;
        }
#pragma unroll
        for (int kt = 0; kt < 4; ++kt)
#pragma unroll
            for (int q = 0; q < 4; ++q)
                acc[q] = __builtin_amdgcn_mfma_f32_16x16x32_bf16(afrag[q][kt], bfrag[kt], acc[q], 0, 0, 0);

        // activation: lane holds i,f,g,o for 4 h-indices, batch colb
        float4 hv;
        {
            float* cp = (float*)&c;
            float* hp = (float*)&hv;
#pragma unroll
            for (int r = 0; r < 4; ++r) {
                float ig = fsig(acc[0][r]);
                float fg = fsig(acc[1][r]);
                float gg = ftanh(acc[2][r]);
                float og = fsig(acc[3][r]);
                float cn = fmaf(fg, cp[r], ig * gg);
                cp[r] = cn;
                hp[r] = og * ftanh(cn);
            }
        }
        *(float4*)(Hc + ((size_t)b * Tc + t) * H_ + hi0) = hv;
        uint2 p;
        p.x = cvt_pk_bf16(hv.x, hv.y);
        p.y = cvt_pk_bf16(hv.z, hv.w);
        *(uint2*)((char*)hbuf[chain][cur ^ 1] + wr_off) = p;
        hlast = hv;
#pragma unroll
        for (int q = 0; q < 4; ++q) pre[q] = preN[q];
        cur ^= 1;
        __syncthreads();
    }

    *(float4*)(hstate + (size_t)b * H_ + hi0) = hlast;
    *(float4*)(cstate + (size_t)b * H_ + hi0) = c;
}

// ---------------------------------------------------------------------------
// mu/logvar GEMMs + z + KL partial, per chunk. grid = B*Tc/64, block 256.
// ---------------------------------------------------------------------------
__global__ __launch_bounds__(256) void mu_logvar_z_kernel(
    const float* __restrict__ Hc,
    const float* __restrict__ Wmu, const float* __restrict__ bmu,
    const float* __restrict__ Wlv, const float* __restrict__ blv,
    const float* __restrict__ epsBase, long epsStride, int lg,
    float* __restrict__ Zc,
    float* __restrict__ klpart)
{
    __shared__ __align__(16) float As[32][68];
    __shared__ __align__(16) float Bmu[32][132];
    __shared__ __align__(16) float Blv[32][132];
    __shared__ float redbuf[8];

    const int m_base = blockIdx.x * 64;
    const int tid = threadIdx.x;
    const int tx = tid & 31, ty = tid >> 5;
    const int n0 = tx * 4;

    float amu[8][4] = {};
    float alv[8][4] = {};

    for (int k0 = 0; k0 < 128; k0 += 32) {
#pragma unroll
        for (int r = 0; r < 2; ++r) {
            int f4 = tid + r * 256;
            int m = f4 >> 3;
            int kq = (f4 & 7) * 4;
            float4 v = *(const float4*)(Hc + (size_t)(m_base + m) * H_ + (k0 + kq));
            As[kq + 0][m] = v.x; As[kq + 1][m] = v.y; As[kq + 2][m] = v.z; As[kq + 3][m] = v.w;
        }
#pragma unroll
        for (int r = 0; r < 4; ++r) {
            int f4 = tid + r * 256;
            int n = f4 >> 3;
            int kq = (f4 & 7) * 4;
            float4 v = *(const float4*)(Wmu + (size_t)n * H_ + (k0 + kq));
            Bmu[kq + 0][n] = v.x; Bmu[kq + 1][n] = v.y; Bmu[kq + 2][n] = v.z; Bmu[kq + 3][n] = v.w;
            float4 u = *(const float4*)(Wlv + (size_t)n * H_ + (k0 + kq));
            Blv[kq + 0][n] = u.x; Blv[kq + 1][n] = u.y; Blv[kq + 2][n] = u.z; Blv[kq + 3][n] = u.w;
        }
        __syncthreads();
#pragma unroll 4
        for (int k = 0; k < 32; ++k) {
            float4 a0 = *(const float4*)&As[k][ty * 8];
            float4 a1 = *(const float4*)&As[k][ty * 8 + 4];
            float4 bm4 = *(const float4*)&Bmu[k][n0];
            float4 bl4 = *(const float4*)&Blv[k][n0];
            float a_[8] = {a0.x, a0.y, a0.z, a0.w, a1.x, a1.y, a1.z, a1.w};
            float bm_[4] = {bm4.x, bm4.y, bm4.z, bm4.w};
            float bl_[4] = {bl4.x, bl4.y, bl4.z, bl4.w};
#pragma unroll
            for (int i = 0; i < 8; ++i)
#pragma unroll
                for (int j = 0; j < 4; ++j) {
                    amu[i][j] = fmaf(a_[i], bm_[j], amu[i][j]);
                    alv[i][j] = fmaf(a_[i], bl_[j], alv[i][j]);
                }
        }
        __syncthreads();
    }

    float4 bmu4 = *(const float4*)(bmu + n0);
    float4 blv4 = *(const float4*)(blv + n0);
    float bm_[4] = {bmu4.x, bmu4.y, bmu4.z, bmu4.w};
    float bl_[4] = {blv4.x, blv4.y, blv4.z, blv4.w};

    float kls = 0.f;
#pragma unroll
    for (int i = 0; i < 8; ++i) {
        int row = m_base + ty * 8 + i;
        float4 e4 = *(const float4*)(epsBase + rowOff(row, lg, epsStride, L_) + n0);
        float e_[4] = {e4.x, e4.y, e4.z, e4.w};
        float z_[4];
#pragma unroll
        for (int j = 0; j < 4; ++j) {
            float mu = amu[i][j] + bm_[j];
            float lv = alv[i][j] + bl_[j];
            z_[j] = fmaf(e_[j], __expf(0.5f * lv), mu);
            kls += 1.0f + lv - mu * mu - __expf(lv);
        }
        *(float4*)(Zc + (size_t)row * L_ + n0) = make_float4(z_[0], z_[1], z_[2], z_[3]);
    }

#pragma unroll
    for (int o = 32; o > 0; o >>= 1) kls += __shfl_down(kls, o);
    int w = tid >> 6, l = tid & 63;
    if (l == 0) redbuf[w] = kls;
    __syncthreads();
    if (tid == 0)
        klpart[blockIdx.x] = redbuf[0] + redbuf[1] + redbuf[2] + redbuf[3];
}

// ---------------------------------------------------------------------------
__global__ __launch_bounds__(256) void cc_kernel(const float* __restrict__ CB, float* __restrict__ cc)
{
    int k = blockIdx.x * 256 + threadIdx.x;
    const float4* r = (const float4*)(CB + (size_t)k * L_);
    float s = 0.f;
#pragma unroll
    for (int i = 0; i < 32; ++i) {
        float4 v = r[i];
        s += v.x * v.x + v.y * v.y + v.z * v.z + v.w * v.w;
    }
    cc[k] = s;
}

// ---------------------------------------------------------------------------
// VQ per chunk: distances + argmin + idx write + SSE partial.
// ---------------------------------------------------------------------------
__global__ __launch_bounds__(256) void vq_kernel(
    const float* __restrict__ Zc,
    const float* __restrict__ CB,
    const float* __restrict__ cc,
    float* __restrict__ idxBase, int lg,
    float* __restrict__ ssepart)
{
    __shared__ __align__(16) float Zs[128][68];
    __shared__ __align__(16) float Cs[128][68];
    __shared__ float zz_s[64];
    __shared__ float dred[64][16];
    __shared__ int kred[64][16];
    __shared__ int kbest_s[64];
    __shared__ float redbuf[8];

    const int m_base = blockIdx.x * 64;
    const int tid = threadIdx.x;
    const int tx = tid & 15, ty = tid >> 4;

#pragma unroll
    for (int cc4 = 0; cc4 < 4; ++cc4) {
#pragma unroll
        for (int r = 0; r < 2; ++r) {
            int f4 = tid + r * 256;
            int m = f4 >> 3;
            int kq = (f4 & 7) * 4;
            int k = cc4 * 32 + kq;
            float4 v = *(const float4*)(Zc + (size_t)(m_base + m) * L_ + k);
            Zs[k + 0][m] = v.x; Zs[k + 1][m] = v.y; Zs[k + 2][m] = v.z; Zs[k + 3][m] = v.w;
        }
    }
    __syncthreads();
    if (tid < 64) {
        float s = 0.f;
        for (int k = 0; k < 128; ++k) { float zv = Zs[k][tid]; s = fmaf(zv, zv, s); }
        zz_s[tid] = s;
    }

    float dmin[4] = {3.4e38f, 3.4e38f, 3.4e38f, 3.4e38f};
    int kmin[4] = {0, 0, 0, 0};

    for (int nt = 0; nt < 16; ++nt) {
        __syncthreads();
#pragma unroll
        for (int cc4 = 0; cc4 < 4; ++cc4) {
#pragma unroll
            for (int r = 0; r < 2; ++r) {
                int f4 = tid + r * 256;
                int n = f4 >> 3;
                int kq = (f4 & 7) * 4;
                int k = cc4 * 32 + kq;
                float4 v = *(const float4*)(CB + (size_t)(nt * 64 + n) * L_ + k);
                Cs[k + 0][n] = v.x; Cs[k + 1][n] = v.y; Cs[k + 2][n] = v.z; Cs[k + 3][n] = v.w;
            }
        }
        __syncthreads();

        float acc[4][4] = {};
#pragma unroll 4
        for (int k = 0; k < 128; ++k) {
            float4 a4 = *(const float4*)&Zs[k][ty * 4];
            float4 b4 = *(const float4*)&Cs[k][tx * 4];
            float a_[4] = {a4.x, a4.y, a4.z, a4.w};
            float b_[4] = {b4.x, b4.y, b4.z, b4.w};
#pragma unroll
            for (int i = 0; i < 4; ++i)
#pragma unroll
                for (int j = 0; j < 4; ++j)
                    acc[i][j] = fmaf(a_[i], b_[j], acc[i][j]);
        }

#pragma unroll
        for (int i = 0; i < 4; ++i) {
            float zzv = zz_s[ty * 4 + i];
#pragma unroll
            for (int j = 0; j < 4; ++j) {
                int code = nt * 64 + tx * 4 + j;
                float d = (zzv + cc[code]) - 2.0f * acc[i][j];
                if (d < dmin[i]) { dmin[i] = d; kmin[i] = code; }
            }
        }
    }

#pragma unroll
    for (int i = 0; i < 4; ++i) {
        dred[ty * 4 + i][tx] = dmin[i];
        kred[ty * 4 + i][tx] = kmin[i];
    }
    __syncthreads();
    if (tid < 64) {
        int r = tid;
        float bd = dred[r][0];
        int bk = kred[r][0];
#pragma unroll
        for (int t = 1; t < 16; ++t) {
            float d = dred[r][t];
            if (d < bd) { bd = d; bk = kred[r][t]; }
        }
        kbest_s[r] = bk;
        int rg = m_base + r;
        idxBase[(size_t)(rg >> lg) * T_ + (rg & ((1 << lg) - 1))] = (float)bk;
    }
    __syncthreads();

    float sse = 0.f;
#pragma unroll
    for (int r = 0; r < 8; ++r) {
        int f4 = tid + r * 256;
        int row = f4 >> 5;
        int cq = (f4 & 31) * 4;
        int kb = kbest_s[row];
        float4 qv = *(const float4*)(CB + (size_t)kb * L_ + cq);
        float4 zv = *(const float4*)(Zc + (size_t)(m_base + row) * L_ + cq);
        float dx = qv.x - zv.x, dy = qv.y - zv.y, dz = qv.z - zv.z, dw = qv.w - zv.w;
        sse += dx * dx + dy * dy + dz * dz + dw * dw;
    }
#pragma unroll
    for (int o = 32; o > 0; o >>= 1) sse += __shfl_down(sse, o);
    int w = tid >> 6, l = tid & 63;
    if (l == 0) redbuf[w] = sse;
    __syncthreads();
    if (tid == 0)
        ssepart[blockIdx.x] = redbuf[0] + redbuf[1] + redbuf[2] + redbuf[3];
}

// ---------------------------------------------------------------------------
__global__ __launch_bounds__(256) void finalize_kernel(
    const float* __restrict__ klpart, const float* __restrict__ ssepart,
    float* __restrict__ loss_out)
{
    float skl = 0.f, ssse = 0.f;
    for (int i = threadIdx.x; i < 2048; i += 256) { skl += klpart[i]; ssse += ssepart[i]; }
#pragma unroll
    for (int o = 32; o > 0; o >>= 1) { skl += __shfl_down(skl, o); ssse += __shfl_down(ssse, o); }
    __shared__ float s1[4], s2[4];
    int w = threadIdx.x >> 6, l = threadIdx.x & 63;
    if (l == 0) { s1[w] = skl; s2[w] = ssse; }
    __syncthreads();
    if (threadIdx.x == 0) {
        float K = s1[0] + s1[1] + s1[2] + s1[3];
        float S = s2[0] + s2[1] + s2[2] + s2[3];
        loss_out[0] = 1.25f * (S / 16777216.0f) - 0.5f * K;
    }
}

// ---------------------------------------------------------------------------
extern "C" void kernel_launch(void* const* d_in, const int* in_sizes, int n_in,
                              void* d_out, int out_size, void* d_ws, size_t ws_size,
                              hipStream_t stream)
{
    const float* traj     = (const float*)d_in[0];
    const float* eps      = (const float*)d_in[1];
    const float* enc_Wih  = (const float*)d_in[2];
    const float* enc_Whh  = (const float*)d_in[3];
    const float* enc_bih  = (const float*)d_in[4];
    const float* enc_bhh  = (const float*)d_in[5];
    const float* fc_mu_W  = (const float*)d_in[6];
    const float* fc_mu_b  = (const float*)d_in[7];
    const float* fc_lv_W  = (const float*)d_in[8];
    const float* fc_lv_b  = (const float*)d_in[9];
    const float* codebook = (const float*)d_in[10];
    const float* dec_Wih  = (const float*)d_in[11];
    const float* dec_Whh  = (const float*)d_in[12];
    const float* dec_bih  = (const float*)d_in[13];
    const float* dec_bhh  = (const float*)d_in[14];
    const float* dec_fc_W = (const float*)d_in[15];
    const float* dec_fc_b = (const float*)d_in[16];

    float* out   = (float*)d_out;
    float* recon = out;                 // [256,512,96]
    float* loss  = out + 12582912;      // scalar
    float* idxf  = out + 12582913;      // [131072]

    // pick largest chunk Tc that fits in ws_size
    int Tc = 512;
    while (Tc > 16) {
        size_t bytes = 4ull * ((size_t)B_ * Tc * (G_ + H_ + L_) + 524288 + 1024 + 65536 + 4096);
        if (bytes <= ws_size) break;
        Tc >>= 1;
    }
    const int lg = __builtin_ctz(Tc);
    const int nchunks = T_ / Tc;
    const int blocksPerChunk = (B_ * Tc) / 64;

    float* ws = (float*)d_ws;
    float* preXc   = ws;                              // B*Tc*512
    float* Hc      = preXc + (size_t)B_ * Tc * G_;    // B*Tc*128
    float* Zc      = Hc + (size_t)B_ * Tc * H_;       // B*Tc*128
    float* preCB   = Zc + (size_t)B_ * Tc * L_;       // 524288
    float* ccbuf   = preCB + (size_t)K_ * G_;         // 1024
    float* hstate  = ccbuf + 1024;                    // 32768
    float* cstate  = hstate + (size_t)B_ * H_;        // 32768
    float* klpart  = cstate + (size_t)B_ * H_;        // 2048
    float* ssepart = klpart + 2048;                   // 2048

    // preCB = codebook @ dec_Wih^T + dec_bih + dec_bhh  [1024,512]
    gemm_bias_kernel<<<dim3(8, 16), 256, 0, stream>>>(
        codebook, 0, 30, dec_Wih, dec_bih, dec_bhh, preCB, 0, 30, G_, L_);
    cc_kernel<<<4, 256, 0, stream>>>(codebook, ccbuf);
    zero_kernel<<<256, 256, 0, stream>>>(hstate, 2 * B_ * H_);

    // ---- encoder + VQ, chunked over T ----
    for (int ci = 0; ci < nchunks; ++ci) {
        const int t0 = ci * Tc;
        gemm_bias_kernel<<<dim3(8, blocksPerChunk), 256, 0, stream>>>(
            traj + (size_t)t0 * D_, (long)T_ * D_, lg,
            enc_Wih, enc_bih, enc_bhh,
            preXc, 0, 30, G_, D_);
        lstm_mfma_kernel<<<B_ / 32, 1024, 0, stream>>>(
            preXc, nullptr, nullptr, enc_Whh, Hc, hstate, cstate, Tc);
        mu_logvar_z_kernel<<<blocksPerChunk, 256, 0, stream>>>(
            Hc, fc_mu_W, fc_mu_b, fc_lv_W, fc_lv_b,
            eps + (size_t)t0 * L_, (long)T_ * L_, lg,
            Zc, klpart + (size_t)ci * blocksPerChunk);
        vq_kernel<<<blocksPerChunk, 256, 0, stream>>>(
            Zc, codebook, ccbuf, idxf + t0, lg,
            ssepart + (size_t)ci * blocksPerChunk);
    }

    zero_kernel<<<256, 256, 0, stream>>>(hstate, 2 * B_ * H_);

    // ---- decoder + recon, chunked over T ----
    for (int ci = 0; ci < nchunks; ++ci) {
        const int t0 = ci * Tc;
        lstm_mfma_kernel<<<B_ / 32, 1024, 0, stream>>>(
            nullptr, idxf + t0, preCB, dec_Whh, Hc, hstate, cstate, Tc);
        gemm_bias_kernel<<<dim3(2, blocksPerChunk), 256, 0, stream>>>(
            Hc, 0, 30, dec_fc_W, dec_fc_b, nullptr,
            recon + (size_t)t0 * D_, (long)T_ * D_, lg, D_, H_);
    }

    finalize_kernel<<<1, 256, 0, stream>>>(klpart, ssepart, loss);
}

// Round 5
// 1832.586 us; speedup vs baseline: 2.5225x; 2.5225x over previous
//
#include <hip/hip_runtime.h>
#include <cstddef>
#include <cstdint>

// VQ-VAE segment, chunked pipeline. Round 5: k-split VALU LSTM on all 256 CUs.
// B=256 T=512 D=96 H=128 4H=512 L=128 K=1024.
// LSTM: 256 blocks (1 batch/CU) x 512 threads. Thread (hi,kg) = tid(kg*128+hi)
// computes partials of gate rows {hi+128q} over k in [32kg,32kg+32) with the
// Whh slice in 128 VGPRs; h read from LDS is 128B/lane/step (4x less than r2).
// Partials exchanged via LDS float4 [kg][hi]; threads 0..127 reduce + activate
// (c in-register), fp32 end-to-end.

#define B_ 256
#define T_ 512
#define D_ 96
#define H_ 128
#define G_ 512
#define L_ 128
#define K_ 1024

__device__ __forceinline__ float fsig(float x) { return 1.0f / (1.0f + __expf(-x)); }
__device__ __forceinline__ float ftanh(float x) { return 1.0f - 2.0f / (1.0f + __expf(2.0f * x)); }

__device__ __forceinline__ size_t rowOff(int m, int lg, long stride, int len) {
    return (size_t)(m >> lg) * (size_t)stride + (size_t)(m & ((1 << lg) - 1)) * (size_t)len;
}

__global__ __launch_bounds__(256) void zero_kernel(float* __restrict__ p, int n)
{
    int i = blockIdx.x * 256 + threadIdx.x;
    if (i < n) p[i] = 0.f;
}

// ---------------------------------------------------------------------------
// C[m,n] = dot(Arow(m), W[n]) + b0[n] (+b1[n]).  BM=BN=64, BK=32, block 256.
// ---------------------------------------------------------------------------
__global__ __launch_bounds__(256) void gemm_bias_kernel(
    const float* __restrict__ A, long aStride, int lgA,
    const float* __restrict__ W,
    const float* __restrict__ b0, const float* __restrict__ b1,
    float* __restrict__ C, long cStride, int lgC,
    int N, int K)
{
    __shared__ __align__(16) float As[32][68];
    __shared__ __align__(16) float Bs[32][68];
    const int n_base = blockIdx.x * 64, m_base = blockIdx.y * 64;
    const int tid = threadIdx.x;
    const int tx = tid & 15, ty = tid >> 4;

    float acc[4][4] = {};

    for (int k0 = 0; k0 < K; k0 += 32) {
#pragma unroll
        for (int r = 0; r < 2; ++r) {
            int f4 = tid + r * 256;
            int m = f4 >> 3;
            int kq = (f4 & 7) * 4;
            float4 v = *(const float4*)(A + rowOff(m_base + m, lgA, aStride, K) + (k0 + kq));
            As[kq + 0][m] = v.x; As[kq + 1][m] = v.y; As[kq + 2][m] = v.z; As[kq + 3][m] = v.w;
            float4 wv = make_float4(0.f, 0.f, 0.f, 0.f);
            if (n_base + m < N)
                wv = *(const float4*)(W + (size_t)(n_base + m) * K + (k0 + kq));
            Bs[kq + 0][m] = wv.x; Bs[kq + 1][m] = wv.y; Bs[kq + 2][m] = wv.z; Bs[kq + 3][m] = wv.w;
        }
        __syncthreads();
#pragma unroll
        for (int k = 0; k < 32; ++k) {
            float4 a4 = *(const float4*)&As[k][ty * 4];
            float4 b4 = *(const float4*)&Bs[k][tx * 4];
            float a_[4] = {a4.x, a4.y, a4.z, a4.w};
            float b_[4] = {b4.x, b4.y, b4.z, b4.w};
#pragma unroll
            for (int i = 0; i < 4; ++i)
#pragma unroll
                for (int j = 0; j < 4; ++j)
                    acc[i][j] = fmaf(a_[i], b_[j], acc[i][j]);
        }
        __syncthreads();
    }

#pragma unroll
    for (int i = 0; i < 4; ++i) {
        int m = m_base + ty * 4 + i;
        size_t cro = rowOff(m, lgC, cStride, N);
#pragma unroll
        for (int j = 0; j < 4; ++j) {
            int n = n_base + tx * 4 + j;
            if (n < N) {
                float bias = (b0 ? b0[n] : 0.f) + (b1 ? b1[n] : 0.f);
                C[cro + n] = acc[i][j] + bias;
            }
        }
    }
}

// ---------------------------------------------------------------------------
// k-split LSTM. grid = B (1 block/CU), block = 512. tid = kg*128 + hi.
// Thread (hi,kg): partial dots of rows {hi+128q | q=0..3} over k in [32kg,+32).
// preX[row] folded into partial q==kg. Threads 0..127 reduce + activate.
// ---------------------------------------------------------------------------
__global__ __launch_bounds__(512) void lstm_kernel(
    const float* __restrict__ preXc,    // [B][Tc][512] or nullptr
    const float* __restrict__ idxBase,  // idxf + t0 (row stride T_) or nullptr
    const float* __restrict__ preCB,    // [1024][512]
    const float* __restrict__ Whh,      // [512][128]
    float* __restrict__ Hc,             // [B][Tc][128]
    float* __restrict__ hstate,         // [B][128]
    float* __restrict__ cstate,         // [B][128]
    int Tc)
{
    __shared__ __align__(16) float hs[H_];          // current h
    __shared__ __align__(16) float4 part[4][H_];    // [kg][hi] partials (i,f,g,o)

    const int b = blockIdx.x;
    const int tid = threadIdx.x;
    const int hi = tid & 127;
    const int kg = tid >> 7;            // k-window [32kg, 32kg+32)

    // Whh slices -> registers: w[q*8+j] = Whh[row=q*128+hi][kg*32+j*4 ..+4)
    float4 w[32];
#pragma unroll
    for (int q = 0; q < 4; ++q) {
        const float* wr = Whh + (size_t)(q * 128 + hi) * H_ + kg * 32;
#pragma unroll
        for (int j = 0; j < 8; ++j)
            w[q * 8 + j] = *(const float4*)(wr + j * 4);
    }

    float c = 0.f;
    if (tid < H_) {
        c = cstate[(size_t)b * H_ + tid];
        hs[tid] = hstate[(size_t)b * H_ + tid];
    }

    // prime pre for t=0 (element tid = gate row kg*128+hi)
    float pre;
    {
        const float* p0;
        if (preXc) p0 = preXc + (size_t)b * Tc * G_;
        else       p0 = preCB + (size_t)((int)idxBase[(size_t)b * T_]) * G_;
        pre = p0[tid];
    }
    __syncthreads();

    for (int t = 0; t < Tc; ++t) {
        // prefetch next step's pre (hidden under this step's compute)
        float pre_next = 0.f;
        if (t + 1 < Tc) {
            const float* pn;
            if (preXc) pn = preXc + ((size_t)b * Tc + t + 1) * G_;
            else       pn = preCB + (size_t)((int)idxBase[(size_t)b * T_ + t + 1]) * G_;
            pre_next = pn[tid];
        }

        // partial dot products over this thread's k-window (broadcast LDS reads)
        float p0 = 0.f, p1 = 0.f, p2 = 0.f, p3 = 0.f;
        const float* hp = hs + kg * 32;
#pragma unroll
        for (int j = 0; j < 8; ++j) {
            float4 h4 = *(const float4*)(hp + j * 4);
            float4 w0 = w[j], w1 = w[8 + j], w2 = w[16 + j], w3 = w[24 + j];
            p0 = fmaf(w0.x, h4.x, p0); p0 = fmaf(w0.y, h4.y, p0);
            p0 = fmaf(w0.z, h4.z, p0); p0 = fmaf(w0.w, h4.w, p0);
            p1 = fmaf(w1.x, h4.x, p1); p1 = fmaf(w1.y, h4.y, p1);
            p1 = fmaf(w1.z, h4.z, p1); p1 = fmaf(w1.w, h4.w, p1);
            p2 = fmaf(w2.x, h4.x, p2); p2 = fmaf(w2.y, h4.y, p2);
            p2 = fmaf(w2.z, h4.z, p2); p2 = fmaf(w2.w, h4.w, p2);
            p3 = fmaf(w3.x, h4.x, p3); p3 = fmaf(w3.y, h4.y, p3);
            p3 = fmaf(w3.z, h4.z, p3); p3 = fmaf(w3.w, h4.w, p3);
        }
        // fold preX[row] into partial q == kg (wave-uniform branch)
        if      (kg == 0) p0 += pre;
        else if (kg == 1) p1 += pre;
        else if (kg == 2) p2 += pre;
        else              p3 += pre;

        part[kg][hi] = make_float4(p0, p1, p2, p3);
        __syncthreads();

        if (tid < H_) {
            float4 s0 = part[0][hi];
            float4 s1 = part[1][hi];
            float4 s2 = part[2][hi];
            float4 s3 = part[3][hi];
            float gi = (s0.x + s1.x) + (s2.x + s3.x);
            float gf = (s0.y + s1.y) + (s2.y + s3.y);
            float gg = (s0.z + s1.z) + (s2.z + s3.z);
            float go = (s0.w + s1.w) + (s2.w + s3.w);
            float ig = fsig(gi);
            float fg = fsig(gf);
            float gv = ftanh(gg);
            float og = fsig(go);
            c = fmaf(fg, c, ig * gv);
            float h = og * ftanh(c);
            hs[hi] = h;
            Hc[((size_t)b * Tc + t) * H_ + hi] = h;
        }
        pre = pre_next;
        __syncthreads();
    }

    if (tid < H_) {
        hstate[(size_t)b * H_ + tid] = hs[tid];
        cstate[(size_t)b * H_ + tid] = c;
    }
}

// ---------------------------------------------------------------------------
// mu/logvar GEMMs + z + KL partial, per chunk. grid = B*Tc/64, block 256.
// ---------------------------------------------------------------------------
__global__ __launch_bounds__(256) void mu_logvar_z_kernel(
    const float* __restrict__ Hc,
    const float* __restrict__ Wmu, const float* __restrict__ bmu,
    const float* __restrict__ Wlv, const float* __restrict__ blv,
    const float* __restrict__ epsBase, long epsStride, int lg,
    float* __restrict__ Zc,
    float* __restrict__ klpart)
{
    __shared__ __align__(16) float As[32][68];
    __shared__ __align__(16) float Bmu[32][132];
    __shared__ __align__(16) float Blv[32][132];
    __shared__ float redbuf[8];

    const int m_base = blockIdx.x * 64;
    const int tid = threadIdx.x;
    const int tx = tid & 31, ty = tid >> 5;
    const int n0 = tx * 4;

    float amu[8][4] = {};
    float alv[8][4] = {};

    for (int k0 = 0; k0 < 128; k0 += 32) {
#pragma unroll
        for (int r = 0; r < 2; ++r) {
            int f4 = tid + r * 256;
            int m = f4 >> 3;
            int kq = (f4 & 7) * 4;
            float4 v = *(const float4*)(Hc + (size_t)(m_base + m) * H_ + (k0 + kq));
            As[kq + 0][m] = v.x; As[kq + 1][m] = v.y; As[kq + 2][m] = v.z; As[kq + 3][m] = v.w;
        }
#pragma unroll
        for (int r = 0; r < 4; ++r) {
            int f4 = tid + r * 256;
            int n = f4 >> 3;
            int kq = (f4 & 7) * 4;
            float4 v = *(const float4*)(Wmu + (size_t)n * H_ + (k0 + kq));
            Bmu[kq + 0][n] = v.x; Bmu[kq + 1][n] = v.y; Bmu[kq + 2][n] = v.z; Bmu[kq + 3][n] = v.w;
            float4 u = *(const float4*)(Wlv + (size_t)n * H_ + (k0 + kq));
            Blv[kq + 0][n] = u.x; Blv[kq + 1][n] = u.y; Blv[kq + 2][n] = u.z; Blv[kq + 3][n] = u.w;
        }
        __syncthreads();
#pragma unroll 4
        for (int k = 0; k < 32; ++k) {
            float4 a0 = *(const float4*)&As[k][ty * 8];
            float4 a1 = *(const float4*)&As[k][ty * 8 + 4];
            float4 bm4 = *(const float4*)&Bmu[k][n0];
            float4 bl4 = *(const float4*)&Blv[k][n0];
            float a_[8] = {a0.x, a0.y, a0.z, a0.w, a1.x, a1.y, a1.z, a1.w};
            float bm_[4] = {bm4.x, bm4.y, bm4.z, bm4.w};
            float bl_[4] = {bl4.x, bl4.y, bl4.z, bl4.w};
#pragma unroll
            for (int i = 0; i < 8; ++i)
#pragma unroll
                for (int j = 0; j < 4; ++j) {
                    amu[i][j] = fmaf(a_[i], bm_[j], amu[i][j]);
                    alv[i][j] = fmaf(a_[i], bl_[j], alv[i][j]);
                }
        }
        __syncthreads();
    }

    float4 bmu4 = *(const float4*)(bmu + n0);
    float4 blv4 = *(const float4*)(blv + n0);
    float bm_[4] = {bmu4.x, bmu4.y, bmu4.z, bmu4.w};
    float bl_[4] = {blv4.x, blv4.y, blv4.z, blv4.w};

    float kls = 0.f;
#pragma unroll
    for (int i = 0; i < 8; ++i) {
        int row = m_base + ty * 8 + i;
        float4 e4 = *(const float4*)(epsBase + rowOff(row, lg, epsStride, L_) + n0);
        float e_[4] = {e4.x, e4.y, e4.z, e4.w};
        float z_[4];
#pragma unroll
        for (int j = 0; j < 4; ++j) {
            float mu = amu[i][j] + bm_[j];
            float lv = alv[i][j] + bl_[j];
            z_[j] = fmaf(e_[j], __expf(0.5f * lv), mu);
            kls += 1.0f + lv - mu * mu - __expf(lv);
        }
        *(float4*)(Zc + (size_t)row * L_ + n0) = make_float4(z_[0], z_[1], z_[2], z_[3]);
    }

#pragma unroll
    for (int o = 32; o > 0; o >>= 1) kls += __shfl_down(kls, o);
    int w = tid >> 6, l = tid & 63;
    if (l == 0) redbuf[w] = kls;
    __syncthreads();
    if (tid == 0)
        klpart[blockIdx.x] = redbuf[0] + redbuf[1] + redbuf[2] + redbuf[3];
}

// ---------------------------------------------------------------------------
__global__ __launch_bounds__(256) void cc_kernel(const float* __restrict__ CB, float* __restrict__ cc)
{
    int k = blockIdx.x * 256 + threadIdx.x;
    const float4* r = (const float4*)(CB + (size_t)k * L_);
    float s = 0.f;
#pragma unroll
    for (int i = 0; i < 32; ++i) {
        float4 v = r[i];
        s += v.x * v.x + v.y * v.y + v.z * v.z + v.w * v.w;
    }
    cc[k] = s;
}

// ---------------------------------------------------------------------------
// VQ per chunk: distances + argmin + idx write + SSE partial.
// ---------------------------------------------------------------------------
__global__ __launch_bounds__(256) void vq_kernel(
    const float* __restrict__ Zc,
    const float* __restrict__ CB,
    const float* __restrict__ cc,
    float* __restrict__ idxBase, int lg,
    float* __restrict__ ssepart)
{
    __shared__ __align__(16) float Zs[128][68];
    __shared__ __align__(16) float Cs[128][68];
    __shared__ float zz_s[64];
    __shared__ float dred[64][16];
    __shared__ int kred[64][16];
    __shared__ int kbest_s[64];
    __shared__ float redbuf[8];

    const int m_base = blockIdx.x * 64;
    const int tid = threadIdx.x;
    const int tx = tid & 15, ty = tid >> 4;

#pragma unroll
    for (int cc4 = 0; cc4 < 4; ++cc4) {
#pragma unroll
        for (int r = 0; r < 2; ++r) {
            int f4 = tid + r * 256;
            int m = f4 >> 3;
            int kq = (f4 & 7) * 4;
            int k = cc4 * 32 + kq;
            float4 v = *(const float4*)(Zc + (size_t)(m_base + m) * L_ + k);
            Zs[k + 0][m] = v.x; Zs[k + 1][m] = v.y; Zs[k + 2][m] = v.z; Zs[k + 3][m] = v.w;
        }
    }
    __syncthreads();
    if (tid < 64) {
        float s = 0.f;
        for (int k = 0; k < 128; ++k) { float zv = Zs[k][tid]; s = fmaf(zv, zv, s); }
        zz_s[tid] = s;
    }

    float dmin[4] = {3.4e38f, 3.4e38f, 3.4e38f, 3.4e38f};
    int kmin[4] = {0, 0, 0, 0};

    for (int nt = 0; nt < 16; ++nt) {
        __syncthreads();
#pragma unroll
        for (int cc4 = 0; cc4 < 4; ++cc4) {
#pragma unroll
            for (int r = 0; r < 2; ++r) {
                int f4 = tid + r * 256;
                int n = f4 >> 3;
                int kq = (f4 & 7) * 4;
                int k = cc4 * 32 + kq;
                float4 v = *(const float4*)(CB + (size_t)(nt * 64 + n) * L_ + k);
                Cs[k + 0][n] = v.x; Cs[k + 1][n] = v.y; Cs[k + 2][n] = v.z; Cs[k + 3][n] = v.w;
            }
        }
        __syncthreads();

        float acc[4][4] = {};
#pragma unroll 4
        for (int k = 0; k < 128; ++k) {
            float4 a4 = *(const float4*)&Zs[k][ty * 4];
            float4 b4 = *(const float4*)&Cs[k][tx * 4];
            float a_[4] = {a4.x, a4.y, a4.z, a4.w};
            float b_[4] = {b4.x, b4.y, b4.z, b4.w};
#pragma unroll
            for (int i = 0; i < 4; ++i)
#pragma unroll
                for (int j = 0; j < 4; ++j)
                    acc[i][j] = fmaf(a_[i], b_[j], acc[i][j]);
        }

#pragma unroll
        for (int i = 0; i < 4; ++i) {
            float zzv = zz_s[ty * 4 + i];
#pragma unroll
            for (int j = 0; j < 4; ++j) {
                int code = nt * 64 + tx * 4 + j;
                float d = (zzv + cc[code]) - 2.0f * acc[i][j];
                if (d < dmin[i]) { dmin[i] = d; kmin[i] = code; }
            }
        }
    }

#pragma unroll
    for (int i = 0; i < 4; ++i) {
        dred[ty * 4 + i][tx] = dmin[i];
        kred[ty * 4 + i][tx] = kmin[i];
    }
    __syncthreads();
    if (tid < 64) {
        int r = tid;
        float bd = dred[r][0];
        int bk = kred[r][0];
#pragma unroll
        for (int t = 1; t < 16; ++t) {
            float d = dred[r][t];
            if (d < bd) { bd = d; bk = kred[r][t]; }
        }
        kbest_s[r] = bk;
        int rg = m_base + r;
        idxBase[(size_t)(rg >> lg) * T_ + (rg & ((1 << lg) - 1))] = (float)bk;
    }
    __syncthreads();

    float sse = 0.f;
#pragma unroll
    for (int r = 0; r < 8; ++r) {
        int f4 = tid + r * 256;
        int row = f4 >> 5;
        int cq = (f4 & 31) * 4;
        int kb = kbest_s[row];
        float4 qv = *(const float4*)(CB + (size_t)kb * L_ + cq);
        float4 zv = *(const float4*)(Zc + (size_t)(m_base + row) * L_ + cq);
        float dx = qv.x - zv.x, dy = qv.y - zv.y, dz = qv.z - zv.z, dw = qv.w - zv.w;
        sse += dx * dx + dy * dy + dz * dz + dw * dw;
    }
#pragma unroll
    for (int o = 32; o > 0; o >>= 1) sse += __shfl_down(sse, o);
    int w = tid >> 6, l = tid & 63;
    if (l == 0) redbuf[w] = sse;
    __syncthreads();
    if (tid == 0)
        ssepart[blockIdx.x] = redbuf[0] + redbuf[1] + redbuf[2] + redbuf[3];
}

// ---------------------------------------------------------------------------
__global__ __launch_bounds__(256) void finalize_kernel(
    const float* __restrict__ klpart, const float* __restrict__ ssepart,
    float* __restrict__ loss_out)
{
    float skl = 0.f, ssse = 0.f;
    for (int i = threadIdx.x; i < 2048; i += 256) { skl += klpart[i]; ssse += ssepart[i]; }
#pragma unroll
    for (int o = 32; o > 0; o >>= 1) { skl += __shfl_down(skl, o); ssse += __shfl_down(ssse, o); }
    __shared__ float s1[4], s2[4];
    int w = threadIdx.x >> 6, l = threadIdx.x & 63;
    if (l == 0) { s1[w] = skl; s2[w] = ssse; }
    __syncthreads();
    if (threadIdx.x == 0) {
        float K = s1[0] + s1[1] + s1[2] + s1[3];
        float S = s2[0] + s2[1] + s2[2] + s2[3];
        loss_out[0] = 1.25f * (S / 16777216.0f) - 0.5f * K;
    }
}

// ---------------------------------------------------------------------------
extern "C" void kernel_launch(void* const* d_in, const int* in_sizes, int n_in,
                              void* d_out, int out_size, void* d_ws, size_t ws_size,
                              hipStream_t stream)
{
    const float* traj     = (const float*)d_in[0];
    const float* eps      = (const float*)d_in[1];
    const float* enc_Wih  = (const float*)d_in[2];
    const float* enc_Whh  = (const float*)d_in[3];
    const float* enc_bih  = (const float*)d_in[4];
    const float* enc_bhh  = (const float*)d_in[5];
    const float* fc_mu_W  = (const float*)d_in[6];
    const float* fc_mu_b  = (const float*)d_in[7];
    const float* fc_lv_W  = (const float*)d_in[8];
    const float* fc_lv_b  = (const float*)d_in[9];
    const float* codebook = (const float*)d_in[10];
    const float* dec_Wih  = (const float*)d_in[11];
    const float* dec_Whh  = (const float*)d_in[12];
    const float* dec_bih  = (const float*)d_in[13];
    const float* dec_bhh  = (const float*)d_in[14];
    const float* dec_fc_W = (const float*)d_in[15];
    const float* dec_fc_b = (const float*)d_in[16];

    float* out   = (float*)d_out;
    float* recon = out;                 // [256,512,96]
    float* loss  = out + 12582912;      // scalar
    float* idxf  = out + 12582913;      // [131072]

    // pick largest chunk Tc that fits in ws_size
    int Tc = 512;
    while (Tc > 16) {
        size_t bytes = 4ull * ((size_t)B_ * Tc * (G_ + H_ + L_) + 524288 + 1024 + 65536 + 4096);
        if (bytes <= ws_size) break;
        Tc >>= 1;
    }
    const int lg = __builtin_ctz(Tc);
    const int nchunks = T_ / Tc;
    const int blocksPerChunk = (B_ * Tc) / 64;

    float* ws = (float*)d_ws;
    float* preXc   = ws;                              // B*Tc*512
    float* Hc      = preXc + (size_t)B_ * Tc * G_;    // B*Tc*128
    float* Zc      = Hc + (size_t)B_ * Tc * H_;       // B*Tc*128
    float* preCB   = Zc + (size_t)B_ * Tc * L_;       // 524288
    float* ccbuf   = preCB + (size_t)K_ * G_;         // 1024
    float* hstate  = ccbuf + 1024;                    // 32768
    float* cstate  = hstate + (size_t)B_ * H_;        // 32768
    float* klpart  = cstate + (size_t)B_ * H_;        // 2048
    float* ssepart = klpart + 2048;                   // 2048

    // preCB = codebook @ dec_Wih^T + dec_bih + dec_bhh  [1024,512]
    gemm_bias_kernel<<<dim3(8, 16), 256, 0, stream>>>(
        codebook, 0, 30, dec_Wih, dec_bih, dec_bhh, preCB, 0, 30, G_, L_);
    cc_kernel<<<4, 256, 0, stream>>>(codebook, ccbuf);
    zero_kernel<<<256, 256, 0, stream>>>(hstate, 2 * B_ * H_);

    // ---- encoder + VQ, chunked over T ----
    for (int ci = 0; ci < nchunks; ++ci) {
        const int t0 = ci * Tc;
        gemm_bias_kernel<<<dim3(8, blocksPerChunk), 256, 0, stream>>>(
            traj + (size_t)t0 * D_, (long)T_ * D_, lg,
            enc_Wih, enc_bih, enc_bhh,
            preXc, 0, 30, G_, D_);
        lstm_kernel<<<B_, 512, 0, stream>>>(
            preXc, nullptr, nullptr, enc_Whh, Hc, hstate, cstate, Tc);
        mu_logvar_z_kernel<<<blocksPerChunk, 256, 0, stream>>>(
            Hc, fc_mu_W, fc_mu_b, fc_lv_W, fc_lv_b,
            eps + (size_t)t0 * L_, (long)T_ * L_, lg,
            Zc, klpart + (size_t)ci * blocksPerChunk);
        vq_kernel<<<blocksPerChunk, 256, 0, stream>>>(
            Zc, codebook, ccbuf, idxf + t0, lg,
            ssepart + (size_t)ci * blocksPerChunk);
    }

    zero_kernel<<<256, 256, 0, stream>>>(hstate, 2 * B_ * H_);

    // ---- decoder + recon, chunked over T ----
    for (int ci = 0; ci < nchunks; ++ci) {
        const int t0 = ci * Tc;
        lstm_kernel<<<B_, 512, 0, stream>>>(
            nullptr, idxf + t0, preCB, dec_Whh, Hc, hstate, cstate, Tc);
        gemm_bias_kernel<<<dim3(2, blocksPerChunk), 256, 0, stream>>>(
            Hc, 0, 30, dec_fc_W, dec_fc_b, nullptr,
            recon + (size_t)t0 * D_, (long)T_ * D_, lg, D_, H_);
    }

    finalize_kernel<<<1, 256, 0, stream>>>(klpart, ssepart, loss);
}

// Round 6
// 1809.400 us; speedup vs baseline: 2.5548x; 1.0128x over previous
//
#include <hip/hip_runtime.h>
#include <cstddef>
#include <cstdint>

// VQ-VAE segment, chunked pipeline. Round 6: split-bf16 MFMA VQ.
// B=256 T=512 D=96 H=128 4H=512 L=128 K=1024.
// VQ: score = z@cb^T via 3x mfma_f32_16x16x32_bf16 with hi/lo split operands
// (rel err ~1e-7, far below np's own fp32 ulp noise on d). No LDS staging.
// LSTM: k-split VALU (r5, unchanged). Decoder input proj = preCB[idx] gather.

#define B_ 256
#define T_ 512
#define D_ 96
#define H_ 128
#define G_ 512
#define L_ 128
#define K_ 1024

typedef __attribute__((ext_vector_type(8))) short bf16x8;
typedef __attribute__((ext_vector_type(4))) float f32x4;

__device__ __forceinline__ float fsig(float x) { return 1.0f / (1.0f + __expf(-x)); }
__device__ __forceinline__ float ftanh(float x) { return 1.0f - 2.0f / (1.0f + __expf(2.0f * x)); }

__device__ __forceinline__ ushort f2bf(float f) {
    union { float f; uint u; } v; v.f = f;
    uint u = v.u;
    return (ushort)((u + 0x7FFFu + ((u >> 16) & 1u)) >> 16);
}
__device__ __forceinline__ float bf2f(ushort h) {
    union { uint u; float f; } v; v.u = ((uint)h) << 16;
    return v.f;
}

__device__ __forceinline__ size_t rowOff(int m, int lg, long stride, int len) {
    return (size_t)(m >> lg) * (size_t)stride + (size_t)(m & ((1 << lg) - 1)) * (size_t)len;
}

__global__ __launch_bounds__(256) void zero_kernel(float* __restrict__ p, int n)
{
    int i = blockIdx.x * 256 + threadIdx.x;
    if (i < n) p[i] = 0.f;
}

// ---------------------------------------------------------------------------
// Split codebook into bf16 hi/lo. grid=512, block=256 (131072 elements).
// ---------------------------------------------------------------------------
__global__ __launch_bounds__(256) void cbsplit_kernel(
    const float* __restrict__ CB, ushort* __restrict__ cbh, ushort* __restrict__ cbl)
{
    int i = blockIdx.x * 256 + threadIdx.x;
    float v = CB[i];
    ushort h = f2bf(v);
    cbh[i] = h;
    cbl[i] = f2bf(v - bf2f(h));
}

// ---------------------------------------------------------------------------
// C[m,n] = dot(Arow(m), W[n]) + b0[n] (+b1[n]).  BM=BN=64, BK=32, block 256.
// ---------------------------------------------------------------------------
__global__ __launch_bounds__(256) void gemm_bias_kernel(
    const float* __restrict__ A, long aStride, int lgA,
    const float* __restrict__ W,
    const float* __restrict__ b0, const float* __restrict__ b1,
    float* __restrict__ C, long cStride, int lgC,
    int N, int K)
{
    __shared__ __align__(16) float As[32][68];
    __shared__ __align__(16) float Bs[32][68];
    const int n_base = blockIdx.x * 64, m_base = blockIdx.y * 64;
    const int tid = threadIdx.x;
    const int tx = tid & 15, ty = tid >> 4;

    float acc[4][4] = {};

    for (int k0 = 0; k0 < K; k0 += 32) {
#pragma unroll
        for (int r = 0; r < 2; ++r) {
            int f4 = tid + r * 256;
            int m = f4 >> 3;
            int kq = (f4 & 7) * 4;
            float4 v = *(const float4*)(A + rowOff(m_base + m, lgA, aStride, K) + (k0 + kq));
            As[kq + 0][m] = v.x; As[kq + 1][m] = v.y; As[kq + 2][m] = v.z; As[kq + 3][m] = v.w;
            float4 wv = make_float4(0.f, 0.f, 0.f, 0.f);
            if (n_base + m < N)
                wv = *(const float4*)(W + (size_t)(n_base + m) * K + (k0 + kq));
            Bs[kq + 0][m] = wv.x; Bs[kq + 1][m] = wv.y; Bs[kq + 2][m] = wv.z; Bs[kq + 3][m] = wv.w;
        }
        __syncthreads();
#pragma unroll
        for (int k = 0; k < 32; ++k) {
            float4 a4 = *(const float4*)&As[k][ty * 4];
            float4 b4 = *(const float4*)&Bs[k][tx * 4];
            float a_[4] = {a4.x, a4.y, a4.z, a4.w};
            float b_[4] = {b4.x, b4.y, b4.z, b4.w};
#pragma unroll
            for (int i = 0; i < 4; ++i)
#pragma unroll
                for (int j = 0; j < 4; ++j)
                    acc[i][j] = fmaf(a_[i], b_[j], acc[i][j]);
        }
        __syncthreads();
    }

#pragma unroll
    for (int i = 0; i < 4; ++i) {
        int m = m_base + ty * 4 + i;
        size_t cro = rowOff(m, lgC, cStride, N);
#pragma unroll
        for (int j = 0; j < 4; ++j) {
            int n = n_base + tx * 4 + j;
            if (n < N) {
                float bias = (b0 ? b0[n] : 0.f) + (b1 ? b1[n] : 0.f);
                C[cro + n] = acc[i][j] + bias;
            }
        }
    }
}

// ---------------------------------------------------------------------------
// k-split LSTM. grid = B (1 block/CU), block = 512. tid = kg*128 + hi.
// ---------------------------------------------------------------------------
__global__ __launch_bounds__(512) void lstm_kernel(
    const float* __restrict__ preXc,    // [B][Tc][512] or nullptr
    const float* __restrict__ idxBase,  // idxf + t0 (row stride T_) or nullptr
    const float* __restrict__ preCB,    // [1024][512]
    const float* __restrict__ Whh,      // [512][128]
    float* __restrict__ Hc,             // [B][Tc][128]
    float* __restrict__ hstate,         // [B][128]
    float* __restrict__ cstate,         // [B][128]
    int Tc)
{
    __shared__ __align__(16) float hs[H_];
    __shared__ __align__(16) float4 part[4][H_];

    const int b = blockIdx.x;
    const int tid = threadIdx.x;
    const int hi = tid & 127;
    const int kg = tid >> 7;

    float4 w[32];
#pragma unroll
    for (int q = 0; q < 4; ++q) {
        const float* wr = Whh + (size_t)(q * 128 + hi) * H_ + kg * 32;
#pragma unroll
        for (int j = 0; j < 8; ++j)
            w[q * 8 + j] = *(const float4*)(wr + j * 4);
    }

    float c = 0.f;
    if (tid < H_) {
        c = cstate[(size_t)b * H_ + tid];
        hs[tid] = hstate[(size_t)b * H_ + tid];
    }

    float pre;
    {
        const float* p0;
        if (preXc) p0 = preXc + (size_t)b * Tc * G_;
        else       p0 = preCB + (size_t)((int)idxBase[(size_t)b * T_]) * G_;
        pre = p0[tid];
    }
    __syncthreads();

    for (int t = 0; t < Tc; ++t) {
        float pre_next = 0.f;
        if (t + 1 < Tc) {
            const float* pn;
            if (preXc) pn = preXc + ((size_t)b * Tc + t + 1) * G_;
            else       pn = preCB + (size_t)((int)idxBase[(size_t)b * T_ + t + 1]) * G_;
            pre_next = pn[tid];
        }

        float p0 = 0.f, p1 = 0.f, p2 = 0.f, p3 = 0.f;
        const float* hp = hs + kg * 32;
#pragma unroll
        for (int j = 0; j < 8; ++j) {
            float4 h4 = *(const float4*)(hp + j * 4);
            float4 w0 = w[j], w1 = w[8 + j], w2 = w[16 + j], w3 = w[24 + j];
            p0 = fmaf(w0.x, h4.x, p0); p0 = fmaf(w0.y, h4.y, p0);
            p0 = fmaf(w0.z, h4.z, p0); p0 = fmaf(w0.w, h4.w, p0);
            p1 = fmaf(w1.x, h4.x, p1); p1 = fmaf(w1.y, h4.y, p1);
            p1 = fmaf(w1.z, h4.z, p1); p1 = fmaf(w1.w, h4.w, p1);
            p2 = fmaf(w2.x, h4.x, p2); p2 = fmaf(w2.y, h4.y, p2);
            p2 = fmaf(w2.z, h4.z, p2); p2 = fmaf(w2.w, h4.w, p2);
            p3 = fmaf(w3.x, h4.x, p3); p3 = fmaf(w3.y, h4.y, p3);
            p3 = fmaf(w3.z, h4.z, p3); p3 = fmaf(w3.w, h4.w, p3);
        }
        if      (kg == 0) p0 += pre;
        else if (kg == 1) p1 += pre;
        else if (kg == 2) p2 += pre;
        else              p3 += pre;

        part[kg][hi] = make_float4(p0, p1, p2, p3);
        __syncthreads();

        if (tid < H_) {
            float4 s0 = part[0][hi];
            float4 s1 = part[1][hi];
            float4 s2 = part[2][hi];
            float4 s3 = part[3][hi];
            float gi = (s0.x + s1.x) + (s2.x + s3.x);
            float gf = (s0.y + s1.y) + (s2.y + s3.y);
            float gg = (s0.z + s1.z) + (s2.z + s3.z);
            float go = (s0.w + s1.w) + (s2.w + s3.w);
            float ig = fsig(gi);
            float fg = fsig(gf);
            float gv = ftanh(gg);
            float og = fsig(go);
            c = fmaf(fg, c, ig * gv);
            float h = og * ftanh(c);
            hs[hi] = h;
            Hc[((size_t)b * Tc + t) * H_ + hi] = h;
        }
        pre = pre_next;
        __syncthreads();
    }

    if (tid < H_) {
        hstate[(size_t)b * H_ + tid] = hs[tid];
        cstate[(size_t)b * H_ + tid] = c;
    }
}

// ---------------------------------------------------------------------------
// mu/logvar GEMMs + z + KL partial, per chunk. grid = B*Tc/64, block 256.
// ---------------------------------------------------------------------------
__global__ __launch_bounds__(256) void mu_logvar_z_kernel(
    const float* __restrict__ Hc,
    const float* __restrict__ Wmu, const float* __restrict__ bmu,
    const float* __restrict__ Wlv, const float* __restrict__ blv,
    const float* __restrict__ epsBase, long epsStride, int lg,
    float* __restrict__ Zc,
    float* __restrict__ klpart)
{
    __shared__ __align__(16) float As[32][68];
    __shared__ __align__(16) float Bmu[32][132];
    __shared__ __align__(16) float Blv[32][132];
    __shared__ float redbuf[8];

    const int m_base = blockIdx.x * 64;
    const int tid = threadIdx.x;
    const int tx = tid & 31, ty = tid >> 5;
    const int n0 = tx * 4;

    float amu[8][4] = {};
    float alv[8][4] = {};

    for (int k0 = 0; k0 < 128; k0 += 32) {
#pragma unroll
        for (int r = 0; r < 2; ++r) {
            int f4 = tid + r * 256;
            int m = f4 >> 3;
            int kq = (f4 & 7) * 4;
            float4 v = *(const float4*)(Hc + (size_t)(m_base + m) * H_ + (k0 + kq));
            As[kq + 0][m] = v.x; As[kq + 1][m] = v.y; As[kq + 2][m] = v.z; As[kq + 3][m] = v.w;
        }
#pragma unroll
        for (int r = 0; r < 4; ++r) {
            int f4 = tid + r * 256;
            int n = f4 >> 3;
            int kq = (f4 & 7) * 4;
            float4 v = *(const float4*)(Wmu + (size_t)n * H_ + (k0 + kq));
            Bmu[kq + 0][n] = v.x; Bmu[kq + 1][n] = v.y; Bmu[kq + 2][n] = v.z; Bmu[kq + 3][n] = v.w;
            float4 u = *(const float4*)(Wlv + (size_t)n * H_ + (k0 + kq));
            Blv[kq + 0][n] = u.x; Blv[kq + 1][n] = u.y; Blv[kq + 2][n] = u.z; Blv[kq + 3][n] = u.w;
        }
        __syncthreads();
#pragma unroll 4
        for (int k = 0; k < 32; ++k) {
            float4 a0 = *(const float4*)&As[k][ty * 8];
            float4 a1 = *(const float4*)&As[k][ty * 8 + 4];
            float4 bm4 = *(const float4*)&Bmu[k][n0];
            float4 bl4 = *(const float4*)&Blv[k][n0];
            float a_[8] = {a0.x, a0.y, a0.z, a0.w, a1.x, a1.y, a1.z, a1.w};
            float bm_[4] = {bm4.x, bm4.y, bm4.z, bm4.w};
            float bl_[4] = {bl4.x, bl4.y, bl4.z, bl4.w};
#pragma unroll
            for (int i = 0; i < 8; ++i)
#pragma unroll
                for (int j = 0; j < 4; ++j) {
                    amu[i][j] = fmaf(a_[i], bm_[j], amu[i][j]);
                    alv[i][j] = fmaf(a_[i], bl_[j], alv[i][j]);
                }
        }
        __syncthreads();
    }

    float4 bmu4 = *(const float4*)(bmu + n0);
    float4 blv4 = *(const float4*)(blv + n0);
    float bm_[4] = {bmu4.x, bmu4.y, bmu4.z, bmu4.w};
    float bl_[4] = {blv4.x, blv4.y, blv4.z, blv4.w};

    float kls = 0.f;
#pragma unroll
    for (int i = 0; i < 8; ++i) {
        int row = m_base + ty * 8 + i;
        float4 e4 = *(const float4*)(epsBase + rowOff(row, lg, epsStride, L_) + n0);
        float e_[4] = {e4.x, e4.y, e4.z, e4.w};
        float z_[4];
#pragma unroll
        for (int j = 0; j < 4; ++j) {
            float mu = amu[i][j] + bm_[j];
            float lv = alv[i][j] + bl_[j];
            z_[j] = fmaf(e_[j], __expf(0.5f * lv), mu);
            kls += 1.0f + lv - mu * mu - __expf(lv);
        }
        *(float4*)(Zc + (size_t)row * L_ + n0) = make_float4(z_[0], z_[1], z_[2], z_[3]);
    }

#pragma unroll
    for (int o = 32; o > 0; o >>= 1) kls += __shfl_down(kls, o);
    int w = tid >> 6, l = tid & 63;
    if (l == 0) redbuf[w] = kls;
    __syncthreads();
    if (tid == 0)
        klpart[blockIdx.x] = redbuf[0] + redbuf[1] + redbuf[2] + redbuf[3];
}

// ---------------------------------------------------------------------------
__global__ __launch_bounds__(256) void cc_kernel(const float* __restrict__ CB, float* __restrict__ cc)
{
    int k = blockIdx.x * 256 + threadIdx.x;
    const float4* r = (const float4*)(CB + (size_t)k * L_);
    float s = 0.f;
#pragma unroll
    for (int i = 0; i < 32; ++i) {
        float4 v = r[i];
        s += v.x * v.x + v.y * v.y + v.z * v.z + v.w * v.w;
    }
    cc[k] = s;
}

// ---------------------------------------------------------------------------
// MFMA VQ: score = z@cb^T via split-bf16 (3 mfma passes), fp32 accumulate.
// grid = B*Tc/64 (64 tokens/block), block = 256 (4 waves x 16 tokens).
// Wave w: tokens [16w,16w+16). Lane l: cl=l&15, g=l>>4.
// A-frag: z[m_base+16w+cl][kc*32+g*8+..]; B-frag: cb[code= nt*64+sub*16+cl][same k].
// D: col=cl -> code, row=g*4+r -> token. argmin d = cc[code] - 2*acc.
// ---------------------------------------------------------------------------
__global__ __launch_bounds__(256) void vq_kernel(
    const float* __restrict__ Zc,      // [B*Tc,128]
    const ushort* __restrict__ cbh,    // [1024,128] bf16 hi
    const ushort* __restrict__ cbl,    // [1024,128] bf16 lo
    const float* __restrict__ CB,      // [1024,128] fp32
    const float* __restrict__ cc,      // [1024]
    float* __restrict__ idxBase, int lg,
    float* __restrict__ ssepart)
{
    __shared__ float cc_s[K_];
    __shared__ int kbest_s[64];
    __shared__ float redbuf[8];

    const int tid = threadIdx.x;
    const int m_base = blockIdx.x * 64;
    const int w = tid >> 6;
    const int l = tid & 63;
    const int cl = l & 15;
    const int g = l >> 4;

    for (int i = tid; i < K_; i += 256) cc_s[i] = cc[i];

    // A-fragments: split z into bf16 hi/lo
    const float* zr = Zc + (size_t)(m_base + 16 * w + cl) * L_ + g * 8;
    bf16x8 ah[4], al[4];
#pragma unroll
    for (int kc = 0; kc < 4; ++kc) {
        float4 x0 = *(const float4*)(zr + kc * 32);
        float4 x1 = *(const float4*)(zr + kc * 32 + 4);
        float xs[8] = {x0.x, x0.y, x0.z, x0.w, x1.x, x1.y, x1.z, x1.w};
        union { bf16x8 v; ushort u[8]; } Hh, Ll;
#pragma unroll
        for (int j = 0; j < 8; ++j) {
            ushort h = f2bf(xs[j]);
            Hh.u[j] = h;
            Ll.u[j] = f2bf(xs[j] - bf2f(h));
        }
        ah[kc] = Hh.v; al[kc] = Ll.v;
    }
    __syncthreads();

    float dmin[4] = {3.4e38f, 3.4e38f, 3.4e38f, 3.4e38f};
    int kmin[4] = {0, 0, 0, 0};

    for (int nt = 0; nt < 16; ++nt) {
#pragma unroll
        for (int sub = 0; sub < 4; ++sub) {
            const int code = nt * 64 + sub * 16 + cl;
            const ushort* chp = cbh + (size_t)code * L_ + g * 8;
            const ushort* clp = cbl + (size_t)code * L_ + g * 8;
            f32x4 acc = {0.f, 0.f, 0.f, 0.f};
#pragma unroll
            for (int kc = 0; kc < 4; ++kc) {
                bf16x8 bh = *(const bf16x8*)(chp + kc * 32);
                bf16x8 blo = *(const bf16x8*)(clp + kc * 32);
                acc = __builtin_amdgcn_mfma_f32_16x16x32_bf16(ah[kc], bh, acc, 0, 0, 0);
                acc = __builtin_amdgcn_mfma_f32_16x16x32_bf16(al[kc], bh, acc, 0, 0, 0);
                acc = __builtin_amdgcn_mfma_f32_16x16x32_bf16(ah[kc], blo, acc, 0, 0, 0);
            }
            float ccv = cc_s[nt * 64 + sub * 16 + cl];
#pragma unroll
            for (int r = 0; r < 4; ++r) {
                float d = fmaf(-2.0f, acc[r], ccv);
                if (d < dmin[r]) { dmin[r] = d; kmin[r] = code; }
            }
        }
    }

    // cross-lane argmin over the 16 cl-columns (np first-min tie-break)
#pragma unroll
    for (int off = 1; off < 16; off <<= 1) {
#pragma unroll
        for (int r = 0; r < 4; ++r) {
            float od = __shfl_xor(dmin[r], off, 64);
            int ok = __shfl_xor(kmin[r], off, 64);
            if (od < dmin[r] || (od == dmin[r] && ok < kmin[r])) {
                dmin[r] = od; kmin[r] = ok;
            }
        }
    }
    if (cl == 0) {
#pragma unroll
        for (int r = 0; r < 4; ++r) {
            int tl = 16 * w + 4 * g + r;
            kbest_s[tl] = kmin[r];
            int rg = m_base + tl;
            idxBase[(size_t)(rg >> lg) * T_ + (rg & ((1 << lg) - 1))] = (float)kmin[r];
        }
    }
    __syncthreads();

    // SSE from selected codes (fp32 exact)
    float sse = 0.f;
#pragma unroll
    for (int r = 0; r < 8; ++r) {
        int f4 = tid + r * 256;
        int row = f4 >> 5;
        int cq = (f4 & 31) * 4;
        int kb = kbest_s[row];
        float4 qv = *(const float4*)(CB + (size_t)kb * L_ + cq);
        float4 zv = *(const float4*)(Zc + (size_t)(m_base + row) * L_ + cq);
        float dx = qv.x - zv.x, dy = qv.y - zv.y, dz = qv.z - zv.z, dw = qv.w - zv.w;
        sse += dx * dx + dy * dy + dz * dz + dw * dw;
    }
#pragma unroll
    for (int o = 32; o > 0; o >>= 1) sse += __shfl_down(sse, o);
    int wv = tid >> 6, ln = tid & 63;
    if (ln == 0) redbuf[wv] = sse;
    __syncthreads();
    if (tid == 0)
        ssepart[blockIdx.x] = redbuf[0] + redbuf[1] + redbuf[2] + redbuf[3];
}

// ---------------------------------------------------------------------------
__global__ __launch_bounds__(256) void finalize_kernel(
    const float* __restrict__ klpart, const float* __restrict__ ssepart,
    float* __restrict__ loss_out)
{
    float skl = 0.f, ssse = 0.f;
    for (int i = threadIdx.x; i < 2048; i += 256) { skl += klpart[i]; ssse += ssepart[i]; }
#pragma unroll
    for (int o = 32; o > 0; o >>= 1) { skl += __shfl_down(skl, o); ssse += __shfl_down(ssse, o); }
    __shared__ float s1[4], s2[4];
    int w = threadIdx.x >> 6, l = threadIdx.x & 63;
    if (l == 0) { s1[w] = skl; s2[w] = ssse; }
    __syncthreads();
    if (threadIdx.x == 0) {
        float K = s1[0] + s1[1] + s1[2] + s1[3];
        float S = s2[0] + s2[1] + s2[2] + s2[3];
        loss_out[0] = 1.25f * (S / 16777216.0f) - 0.5f * K;
    }
}

// ---------------------------------------------------------------------------
extern "C" void kernel_launch(void* const* d_in, const int* in_sizes, int n_in,
                              void* d_out, int out_size, void* d_ws, size_t ws_size,
                              hipStream_t stream)
{
    const float* traj     = (const float*)d_in[0];
    const float* eps      = (const float*)d_in[1];
    const float* enc_Wih  = (const float*)d_in[2];
    const float* enc_Whh  = (const float*)d_in[3];
    const float* enc_bih  = (const float*)d_in[4];
    const float* enc_bhh  = (const float*)d_in[5];
    const float* fc_mu_W  = (const float*)d_in[6];
    const float* fc_mu_b  = (const float*)d_in[7];
    const float* fc_lv_W  = (const float*)d_in[8];
    const float* fc_lv_b  = (const float*)d_in[9];
    const float* codebook = (const float*)d_in[10];
    const float* dec_Wih  = (const float*)d_in[11];
    const float* dec_Whh  = (const float*)d_in[12];
    const float* dec_bih  = (const float*)d_in[13];
    const float* dec_bhh  = (const float*)d_in[14];
    const float* dec_fc_W = (const float*)d_in[15];
    const float* dec_fc_b = (const float*)d_in[16];

    float* out   = (float*)d_out;
    float* recon = out;                 // [256,512,96]
    float* loss  = out + 12582912;      // scalar
    float* idxf  = out + 12582913;      // [131072]

    // pick largest chunk Tc that fits in ws_size (fixed part incl. split cb)
    int Tc = 512;
    while (Tc > 16) {
        size_t bytes = 4ull * ((size_t)B_ * Tc * (G_ + H_ + L_)
                               + 524288 + 1024 + 65536 + 4096 + 131072);
        if (bytes <= ws_size) break;
        Tc >>= 1;
    }
    const int lg = __builtin_ctz(Tc);
    const int nchunks = T_ / Tc;
    const int blocksPerChunk = (B_ * Tc) / 64;

    float* ws = (float*)d_ws;
    float* preXc   = ws;                              // B*Tc*512
    float* Hc      = preXc + (size_t)B_ * Tc * G_;    // B*Tc*128
    float* Zc      = Hc + (size_t)B_ * Tc * H_;       // B*Tc*128
    float* preCB   = Zc + (size_t)B_ * Tc * L_;       // 524288
    float* ccbuf   = preCB + (size_t)K_ * G_;         // 1024
    float* hstate  = ccbuf + 1024;                    // 32768
    float* cstate  = hstate + (size_t)B_ * H_;        // 32768
    float* klpart  = cstate + (size_t)B_ * H_;        // 2048
    float* ssepart = klpart + 2048;                   // 2048
    ushort* cbh    = (ushort*)(ssepart + 2048);       // 131072 ushort (64K floats)
    ushort* cbl    = cbh + (size_t)K_ * L_;           // 131072 ushort (64K floats)

    // preCB = codebook @ dec_Wih^T + dec_bih + dec_bhh  [1024,512]
    gemm_bias_kernel<<<dim3(8, 16), 256, 0, stream>>>(
        codebook, 0, 30, dec_Wih, dec_bih, dec_bhh, preCB, 0, 30, G_, L_);
    cc_kernel<<<4, 256, 0, stream>>>(codebook, ccbuf);
    cbsplit_kernel<<<512, 256, 0, stream>>>(codebook, cbh, cbl);
    zero_kernel<<<256, 256, 0, stream>>>(hstate, 2 * B_ * H_);

    // ---- encoder + VQ, chunked over T ----
    for (int ci = 0; ci < nchunks; ++ci) {
        const int t0 = ci * Tc;
        gemm_bias_kernel<<<dim3(8, blocksPerChunk), 256, 0, stream>>>(
            traj + (size_t)t0 * D_, (long)T_ * D_, lg,
            enc_Wih, enc_bih, enc_bhh,
            preXc, 0, 30, G_, D_);
        lstm_kernel<<<B_, 512, 0, stream>>>(
            preXc, nullptr, nullptr, enc_Whh, Hc, hstate, cstate, Tc);
        mu_logvar_z_kernel<<<blocksPerChunk, 256, 0, stream>>>(
            Hc, fc_mu_W, fc_mu_b, fc_lv_W, fc_lv_b,
            eps + (size_t)t0 * L_, (long)T_ * L_, lg,
            Zc, klpart + (size_t)ci * blocksPerChunk);
        vq_kernel<<<blocksPerChunk, 256, 0, stream>>>(
            Zc, cbh, cbl, codebook, ccbuf, idxf + t0, lg,
            ssepart + (size_t)ci * blocksPerChunk);
    }

    zero_kernel<<<256, 256, 0, stream>>>(hstate, 2 * B_ * H_);

    // ---- decoder + recon, chunked over T ----
    for (int ci = 0; ci < nchunks; ++ci) {
        const int t0 = ci * Tc;
        lstm_kernel<<<B_, 512, 0, stream>>>(
            nullptr, idxf + t0, preCB, dec_Whh, Hc, hstate, cstate, Tc);
        gemm_bias_kernel<<<dim3(2, blocksPerChunk), 256, 0, stream>>>(
            Hc, 0, 30, dec_fc_W, dec_fc_b, nullptr,
            recon + (size_t)t0 * D_, (long)T_ * D_, lg, D_, H_);
    }

    finalize_kernel<<<1, 256, 0, stream>>>(klpart, ssepart, loss);
}

// Round 7
// 1390.624 us; speedup vs baseline: 3.3242x; 1.3011x over previous
//
#include <hip/hip_runtime.h>
#include <cstddef>
#include <cstdint>

// VQ-VAE segment, chunked pipeline. Round 7:
//  - LSTM: in-wave k-split + fdot2(fp16 weights/h), 1 barrier/step, shuffle reduce.
//  - VQ: split-bf16 MFMA + per-block LDS-staged codebook tiles (XOR-swizzled),
//        3 independent split accumulators.
// B=256 T=512 D=96 H=128 4H=512 L=128 K=1024.

#define B_ 256
#define T_ 512
#define D_ 96
#define H_ 128
#define G_ 512
#define L_ 128
#define K_ 1024

#ifndef __has_builtin
#define __has_builtin(x) 0
#endif
#if __has_builtin(__builtin_amdgcn_fdot2)
#define HAVE_FDOT2 1
#else
#define HAVE_FDOT2 0
#endif

typedef __attribute__((ext_vector_type(8))) short bf16x8;
typedef __attribute__((ext_vector_type(4))) float f32x4;
typedef __attribute__((ext_vector_type(2))) _Float16 half2v;
typedef __attribute__((ext_vector_type(8))) _Float16 half8v;

__device__ __forceinline__ ushort f2bf(float f) {
    union { float f; uint u; } v; v.f = f;
    uint u = v.u;
    return (ushort)((u + 0x7FFFu + ((u >> 16) & 1u)) >> 16);
}
__device__ __forceinline__ float bf2f(ushort h) {
    union { uint u; float f; } v; v.u = ((uint)h) << 16;
    return v.f;
}

__device__ __forceinline__ size_t rowOff(int m, int lg, long stride, int len) {
    return (size_t)(m >> lg) * (size_t)stride + (size_t)(m & ((1 << lg) - 1)) * (size_t)len;
}

__global__ __launch_bounds__(256) void zero_kernel(float* __restrict__ p, int n)
{
    int i = blockIdx.x * 256 + threadIdx.x;
    if (i < n) p[i] = 0.f;
}

// ---------------------------------------------------------------------------
// Split codebook into bf16 hi/lo. grid=512, block=256.
// ---------------------------------------------------------------------------
__global__ __launch_bounds__(256) void cbsplit_kernel(
    const float* __restrict__ CB, ushort* __restrict__ cbh, ushort* __restrict__ cbl)
{
    int i = blockIdx.x * 256 + threadIdx.x;
    float v = CB[i];
    ushort h = f2bf(v);
    cbh[i] = h;
    cbl[i] = f2bf(v - bf2f(h));
}

// ---------------------------------------------------------------------------
// C[m,n] = dot(Arow(m), W[n]) + b0[n] (+b1[n]).  BM=BN=64, BK=32, block 256.
// ---------------------------------------------------------------------------
__global__ __launch_bounds__(256) void gemm_bias_kernel(
    const float* __restrict__ A, long aStride, int lgA,
    const float* __restrict__ W,
    const float* __restrict__ b0, const float* __restrict__ b1,
    float* __restrict__ C, long cStride, int lgC,
    int N, int K)
{
    __shared__ __align__(16) float As[32][68];
    __shared__ __align__(16) float Bs[32][68];
    const int n_base = blockIdx.x * 64, m_base = blockIdx.y * 64;
    const int tid = threadIdx.x;
    const int tx = tid & 15, ty = tid >> 4;

    float acc[4][4] = {};

    for (int k0 = 0; k0 < K; k0 += 32) {
#pragma unroll
        for (int r = 0; r < 2; ++r) {
            int f4 = tid + r * 256;
            int m = f4 >> 3;
            int kq = (f4 & 7) * 4;
            float4 v = *(const float4*)(A + rowOff(m_base + m, lgA, aStride, K) + (k0 + kq));
            As[kq + 0][m] = v.x; As[kq + 1][m] = v.y; As[kq + 2][m] = v.z; As[kq + 3][m] = v.w;
            float4 wv = make_float4(0.f, 0.f, 0.f, 0.f);
            if (n_base + m < N)
                wv = *(const float4*)(W + (size_t)(n_base + m) * K + (k0 + kq));
            Bs[kq + 0][m] = wv.x; Bs[kq + 1][m] = wv.y; Bs[kq + 2][m] = wv.z; Bs[kq + 3][m] = wv.w;
        }
        __syncthreads();
#pragma unroll
        for (int k = 0; k < 32; ++k) {
            float4 a4 = *(const float4*)&As[k][ty * 4];
            float4 b4 = *(const float4*)&Bs[k][tx * 4];
            float a_[4] = {a4.x, a4.y, a4.z, a4.w};
            float b_[4] = {b4.x, b4.y, b4.z, b4.w};
#pragma unroll
            for (int i = 0; i < 4; ++i)
#pragma unroll
                for (int j = 0; j < 4; ++j)
                    acc[i][j] = fmaf(a_[i], b_[j], acc[i][j]);
        }
        __syncthreads();
    }

#pragma unroll
    for (int i = 0; i < 4; ++i) {
        int m = m_base + ty * 4 + i;
        size_t cro = rowOff(m, lgC, cStride, N);
#pragma unroll
        for (int j = 0; j < 4; ++j) {
            int n = n_base + tx * 4 + j;
            if (n < N) {
                float bias = (b0 ? b0[n] : 0.f) + (b1 ? b1[n] : 0.f);
                C[cro + n] = acc[i][j] + bias;
            }
        }
    }
}

// ---------------------------------------------------------------------------
// LSTM: grid = B (1 block/CU), block = 512 (8 waves). Wave w owns
// hi in [16w,16w+16). Lane l: cl=l&15 -> hi=16w+cl, kg=l>>4 -> k-window
// [32kg,32kg+32). Partial dots of gate rows {hi+128q} via fdot2 (fp16 W,h);
// cross-kg reduce by shfl_xor(16/32); uniform-transcendental activation;
// one barrier/step; h double-buffered as fp16 in LDS.
// ---------------------------------------------------------------------------
__global__ __launch_bounds__(512) void lstm_kernel(
    const float* __restrict__ preXc,    // [B][Tc][512] or nullptr
    const float* __restrict__ idxBase,  // idxf + t0 (row stride T_) or nullptr
    const float* __restrict__ preCB,    // [1024][512]
    const float* __restrict__ Whh,      // [512][128]
    float* __restrict__ Hc,             // [B][Tc][128]
    float* __restrict__ hstate,         // [B][128]
    float* __restrict__ cstate,         // [B][128]
    int Tc)
{
    __shared__ __align__(16) _Float16 hbuf[2][H_];

    const int tid = threadIdx.x;
    const int w = tid >> 6;
    const int l = tid & 63;
    const int cl = l & 15;
    const int kg = l >> 4;
    const int b = blockIdx.x;
    const int hi = 16 * w + cl;
    const int prow = kg * 128 + hi;

    // weights for rows {q*128+hi}, k in [32kg, 32kg+32)
#if HAVE_FDOT2
    half2v wz[4][16];
#else
    float wz[4][32];
#endif
#pragma unroll
    for (int q = 0; q < 4; ++q) {
        const float* wr = Whh + (size_t)(q * 128 + hi) * H_ + kg * 32;
#pragma unroll
        for (int j = 0; j < 8; ++j) {
            float4 v = *(const float4*)(wr + j * 4);
#if HAVE_FDOT2
            wz[q][2 * j]     = half2v{(_Float16)v.x, (_Float16)v.y};
            wz[q][2 * j + 1] = half2v{(_Float16)v.z, (_Float16)v.w};
#else
            wz[q][4 * j] = v.x; wz[q][4 * j + 1] = v.y;
            wz[q][4 * j + 2] = v.z; wz[q][4 * j + 3] = v.w;
#endif
        }
    }

    float c = 0.f, hlast = 0.f;
    if (kg == 0) {
        c = cstate[(size_t)b * H_ + hi];
        hlast = hstate[(size_t)b * H_ + hi];
        hbuf[0][hi] = (_Float16)hlast;
    }

    const float* px = preXc ? (preXc + (size_t)b * Tc * G_) : nullptr;
    const float* irow = idxBase ? (idxBase + (size_t)b * T_) : nullptr;

    float pre;
    if (px) pre = px[prow];
    else    pre = preCB[(size_t)((int)irow[0]) * G_ + prow];
    __syncthreads();

    int cur = 0;
    for (int t = 0; t < Tc; ++t) {
        float pre_next = 0.f;
        if (t + 1 < Tc) {
            const float* pn;
            if (px) pn = px + (size_t)(t + 1) * G_;
            else    pn = preCB + (size_t)((int)irow[t + 1]) * G_;
            pre_next = pn[prow];
        }

        // read h window (fp16) and compute 4 gate partials
        union { half8v v8[4]; half2v v2[16]; } hu;
        {
            const half8v* hp = (const half8v*)&hbuf[cur][kg * 32];
#pragma unroll
            for (int j = 0; j < 4; ++j) hu.v8[j] = hp[j];
        }
        float p0 = 0.f, p1 = 0.f, p2 = 0.f, p3 = 0.f;
#if HAVE_FDOT2
#pragma unroll
        for (int m = 0; m < 16; ++m) {
            half2v hp2 = hu.v2[m];
            p0 = __builtin_amdgcn_fdot2(wz[0][m], hp2, p0, false);
            p1 = __builtin_amdgcn_fdot2(wz[1][m], hp2, p1, false);
            p2 = __builtin_amdgcn_fdot2(wz[2][m], hp2, p2, false);
            p3 = __builtin_amdgcn_fdot2(wz[3][m], hp2, p3, false);
        }
#else
        float hf[32];
#pragma unroll
        for (int m = 0; m < 16; ++m) {
            hf[2 * m] = (float)hu.v2[m].x;
            hf[2 * m + 1] = (float)hu.v2[m].y;
        }
#pragma unroll
        for (int k = 0; k < 32; ++k) {
            float hv = hf[k];
            p0 = fmaf(wz[0][k], hv, p0);
            p1 = fmaf(wz[1][k], hv, p1);
            p2 = fmaf(wz[2][k], hv, p2);
            p3 = fmaf(wz[3][k], hv, p3);
        }
#endif
        // fold pre into this lane's gate
        p0 += (kg == 0) ? pre : 0.f;
        p1 += (kg == 1) ? pre : 0.f;
        p2 += (kg == 2) ? pre : 0.f;
        p3 += (kg == 3) ? pre : 0.f;

        // reduce over kg lanes (lane bits 4,5)
        p0 += __shfl_xor(p0, 16); p0 += __shfl_xor(p0, 32);
        p1 += __shfl_xor(p1, 16); p1 += __shfl_xor(p1, 32);
        p2 += __shfl_xor(p2, 16); p2 += __shfl_xor(p2, 32);
        p3 += __shfl_xor(p3, 16); p3 += __shfl_xor(p3, 32);

        // uniform activation: lane kg applies sig (kg!=2) or tanh (kg==2) to gate kg
        float x = (kg & 1) ? ((kg & 2) ? p3 : p1) : ((kg & 2) ? p2 : p0);
        float s = (kg == 2) ? 2.f * x : x;
        float e = __expf(-s);
        float r = 1.0f / (1.0f + e);
        float y = (kg == 2) ? fmaf(2.f, r, -1.f) : r;   // sig or tanh
        float fg = __shfl_xor(y, 16);
        float gg = __shfl_xor(y, 32);
        float og = __shfl_xor(y, 48);
        if (kg == 0) {
            c = fmaf(fg, c, y * gg);                    // y = i gate here
            float th = fmaf(2.f, 1.0f / (1.0f + __expf(-2.f * c)), -1.f);
            float h = og * th;
            hlast = h;
            hbuf[cur ^ 1][hi] = (_Float16)h;
            Hc[((size_t)b * Tc + t) * H_ + hi] = h;
        }
        __syncthreads();
        cur ^= 1;
        pre = pre_next;
    }

    if (kg == 0) {
        hstate[(size_t)b * H_ + hi] = hlast;
        cstate[(size_t)b * H_ + hi] = c;
    }
}

// ---------------------------------------------------------------------------
// mu/logvar GEMMs + z + KL partial, per chunk. grid = B*Tc/64, block 256.
// ---------------------------------------------------------------------------
__global__ __launch_bounds__(256) void mu_logvar_z_kernel(
    const float* __restrict__ Hc,
    const float* __restrict__ Wmu, const float* __restrict__ bmu,
    const float* __restrict__ Wlv, const float* __restrict__ blv,
    const float* __restrict__ epsBase, long epsStride, int lg,
    float* __restrict__ Zc,
    float* __restrict__ klpart)
{
    __shared__ __align__(16) float As[32][68];
    __shared__ __align__(16) float Bmu[32][132];
    __shared__ __align__(16) float Blv[32][132];
    __shared__ float redbuf[8];

    const int m_base = blockIdx.x * 64;
    const int tid = threadIdx.x;
    const int tx = tid & 31, ty = tid >> 5;
    const int n0 = tx * 4;

    float amu[8][4] = {};
    float alv[8][4] = {};

    for (int k0 = 0; k0 < 128; k0 += 32) {
#pragma unroll
        for (int r = 0; r < 2; ++r) {
            int f4 = tid + r * 256;
            int m = f4 >> 3;
            int kq = (f4 & 7) * 4;
            float4 v = *(const float4*)(Hc + (size_t)(m_base + m) * H_ + (k0 + kq));
            As[kq + 0][m] = v.x; As[kq + 1][m] = v.y; As[kq + 2][m] = v.z; As[kq + 3][m] = v.w;
        }
#pragma unroll
        for (int r = 0; r < 4; ++r) {
            int f4 = tid + r * 256;
            int n = f4 >> 3;
            int kq = (f4 & 7) * 4;
            float4 v = *(const float4*)(Wmu + (size_t)n * H_ + (k0 + kq));
            Bmu[kq + 0][n] = v.x; Bmu[kq + 1][n] = v.y; Bmu[kq + 2][n] = v.z; Bmu[kq + 3][n] = v.w;
            float4 u = *(const float4*)(Wlv + (size_t)n * H_ + (k0 + kq));
            Blv[kq + 0][n] = u.x; Blv[kq + 1][n] = u.y; Blv[kq + 2][n] = u.z; Blv[kq + 3][n] = u.w;
        }
        __syncthreads();
#pragma unroll 4
        for (int k = 0; k < 32; ++k) {
            float4 a0 = *(const float4*)&As[k][ty * 8];
            float4 a1 = *(const float4*)&As[k][ty * 8 + 4];
            float4 bm4 = *(const float4*)&Bmu[k][n0];
            float4 bl4 = *(const float4*)&Blv[k][n0];
            float a_[8] = {a0.x, a0.y, a0.z, a0.w, a1.x, a1.y, a1.z, a1.w};
            float bm_[4] = {bm4.x, bm4.y, bm4.z, bm4.w};
            float bl_[4] = {bl4.x, bl4.y, bl4.z, bl4.w};
#pragma unroll
            for (int i = 0; i < 8; ++i)
#pragma unroll
                for (int j = 0; j < 4; ++j) {
                    amu[i][j] = fmaf(a_[i], bm_[j], amu[i][j]);
                    alv[i][j] = fmaf(a_[i], bl_[j], alv[i][j]);
                }
        }
        __syncthreads();
    }

    float4 bmu4 = *(const float4*)(bmu + n0);
    float4 blv4 = *(const float4*)(blv + n0);
    float bm_[4] = {bmu4.x, bmu4.y, bmu4.z, bmu4.w};
    float bl_[4] = {blv4.x, blv4.y, blv4.z, blv4.w};

    float kls = 0.f;
#pragma unroll
    for (int i = 0; i < 8; ++i) {
        int row = m_base + ty * 8 + i;
        float4 e4 = *(const float4*)(epsBase + rowOff(row, lg, epsStride, L_) + n0);
        float e_[4] = {e4.x, e4.y, e4.z, e4.w};
        float z_[4];
#pragma unroll
        for (int j = 0; j < 4; ++j) {
            float mu = amu[i][j] + bm_[j];
            float lv = alv[i][j] + bl_[j];
            z_[j] = fmaf(e_[j], __expf(0.5f * lv), mu);
            kls += 1.0f + lv - mu * mu - __expf(lv);
        }
        *(float4*)(Zc + (size_t)row * L_ + n0) = make_float4(z_[0], z_[1], z_[2], z_[3]);
    }

#pragma unroll
    for (int o = 32; o > 0; o >>= 1) kls += __shfl_down(kls, o);
    int w = tid >> 6, l = tid & 63;
    if (l == 0) redbuf[w] = kls;
    __syncthreads();
    if (tid == 0)
        klpart[blockIdx.x] = redbuf[0] + redbuf[1] + redbuf[2] + redbuf[3];
}

// ---------------------------------------------------------------------------
__global__ __launch_bounds__(256) void cc_kernel(const float* __restrict__ CB, float* __restrict__ cc)
{
    int k = blockIdx.x * 256 + threadIdx.x;
    const float4* r = (const float4*)(CB + (size_t)k * L_);
    float s = 0.f;
#pragma unroll
    for (int i = 0; i < 32; ++i) {
        float4 v = r[i];
        s += v.x * v.x + v.y * v.y + v.z * v.z + v.w * v.w;
    }
    cc[k] = s;
}

// ---------------------------------------------------------------------------
// MFMA VQ with LDS-staged codebook tiles. grid = B*Tc/64, block = 256.
// Per nt (64 codes): block stages hi/lo bf16 rows into XOR-swizzled LDS
// (shared by 4 waves), then each wave runs 3-term split MFMA with
// 3 independent accumulators. d = cc - 2*(hh+lh+hl).
// ---------------------------------------------------------------------------
__global__ __launch_bounds__(256) void vq_kernel(
    const float* __restrict__ Zc,      // [B*Tc,128]
    const ushort* __restrict__ cbh,    // [1024,128] bf16 hi
    const ushort* __restrict__ cbl,    // [1024,128] bf16 lo
    const float* __restrict__ CB,      // [1024,128] fp32
    const float* __restrict__ cc,      // [1024]
    float* __restrict__ idxBase, int lg,
    float* __restrict__ ssepart)
{
    __shared__ __align__(16) ushort cbhs[64 * 128];   // 16KB swizzled
    __shared__ __align__(16) ushort cbls[64 * 128];   // 16KB swizzled
    __shared__ float cc_s[K_];
    __shared__ int kbest_s[64];
    __shared__ float redbuf[8];

    const int tid = threadIdx.x;
    const int m_base = blockIdx.x * 64;
    const int w = tid >> 6;
    const int l = tid & 63;
    const int cl = l & 15;
    const int g = l >> 4;

    for (int i = tid; i < K_; i += 256) cc_s[i] = cc[i];

    // A-fragments: split z into bf16 hi/lo (wave w: tokens 16w..16w+15)
    const float* zr = Zc + (size_t)(m_base + 16 * w + cl) * L_ + g * 8;
    bf16x8 ah[4], al[4];
#pragma unroll
    for (int kc = 0; kc < 4; ++kc) {
        float4 x0 = *(const float4*)(zr + kc * 32);
        float4 x1 = *(const float4*)(zr + kc * 32 + 4);
        float xs[8] = {x0.x, x0.y, x0.z, x0.w, x1.x, x1.y, x1.z, x1.w};
        union { bf16x8 v; ushort u[8]; } Hh, Ll;
#pragma unroll
        for (int j = 0; j < 8; ++j) {
            ushort h = f2bf(xs[j]);
            Hh.u[j] = h;
            Ll.u[j] = f2bf(xs[j] - bf2f(h));
        }
        ah[kc] = Hh.v; al[kc] = Ll.v;
    }

    float dmin[4] = {3.4e38f, 3.4e38f, 3.4e38f, 3.4e38f};
    int kmin[4] = {0, 0, 0, 0};

    for (int nt = 0; nt < 16; ++nt) {
        __syncthreads();   // previous compute done (first: cc_s ready)
        // stage 64 codes (hi+lo) = 1024 x 16B chunks, XOR-swizzled
        {
            const uint4* srcH = (const uint4*)(cbh + (size_t)nt * 64 * 128);
            const uint4* srcL = (const uint4*)(cbl + (size_t)nt * 64 * 128);
#pragma unroll
            for (int r = 0; r < 4; ++r) {
                int idx = tid + r * 256;
                int arr = idx >> 9;
                int rem = idx & 511;
                int code = rem >> 3;
                int chk = rem & 7;
                uint4 v = arr ? srcL[rem] : srcH[rem];
                uint4* dst = arr ? (uint4*)cbls : (uint4*)cbhs;
                dst[code * 8 + (chk ^ (code & 7))] = v;
            }
        }
        __syncthreads();

#pragma unroll
        for (int sub = 0; sub < 4; ++sub) {
            const int crow = sub * 16 + cl;             // code within tile
            const int code = nt * 64 + crow;
            const ushort* bph = cbhs + crow * 128;
            const ushort* bpl = cbls + crow * 128;
            bf16x8 bh[4], bl4[4];
#pragma unroll
            for (int kc = 0; kc < 4; ++kc) {
                int slot = ((kc * 4 + g) ^ (cl & 7)) << 3;
                bh[kc]  = *(const bf16x8*)(bph + slot);
                bl4[kc] = *(const bf16x8*)(bpl + slot);
            }
            f32x4 ahh = {0.f, 0.f, 0.f, 0.f};
            f32x4 alh = {0.f, 0.f, 0.f, 0.f};
            f32x4 ahl = {0.f, 0.f, 0.f, 0.f};
#pragma unroll
            for (int kc = 0; kc < 4; ++kc) {
                ahh = __builtin_amdgcn_mfma_f32_16x16x32_bf16(ah[kc], bh[kc], ahh, 0, 0, 0);
                alh = __builtin_amdgcn_mfma_f32_16x16x32_bf16(al[kc], bh[kc], alh, 0, 0, 0);
                ahl = __builtin_amdgcn_mfma_f32_16x16x32_bf16(ah[kc], bl4[kc], ahl, 0, 0, 0);
            }
            float ccv = cc_s[code];
#pragma unroll
            for (int r = 0; r < 4; ++r) {
                float s = (ahh[r] + alh[r]) + ahl[r];
                float d = fmaf(-2.0f, s, ccv);
                if (d < dmin[r]) { dmin[r] = d; kmin[r] = code; }
            }
        }
    }

    // cross-lane argmin over 16 cl-columns (np first-min tie-break)
#pragma unroll
    for (int off = 1; off < 16; off <<= 1) {
#pragma unroll
        for (int r = 0; r < 4; ++r) {
            float od = __shfl_xor(dmin[r], off, 64);
            int ok = __shfl_xor(kmin[r], off, 64);
            if (od < dmin[r] || (od == dmin[r] && ok < kmin[r])) {
                dmin[r] = od; kmin[r] = ok;
            }
        }
    }
    if (cl == 0) {
#pragma unroll
        for (int r = 0; r < 4; ++r) {
            int tl = 16 * w + 4 * g + r;
            kbest_s[tl] = kmin[r];
            int rg = m_base + tl;
            idxBase[(size_t)(rg >> lg) * T_ + (rg & ((1 << lg) - 1))] = (float)kmin[r];
        }
    }
    __syncthreads();

    // SSE from selected codes (fp32 exact)
    float sse = 0.f;
#pragma unroll
    for (int r = 0; r < 8; ++r) {
        int f4 = tid + r * 256;
        int row = f4 >> 5;
        int cq = (f4 & 31) * 4;
        int kb = kbest_s[row];
        float4 qv = *(const float4*)(CB + (size_t)kb * L_ + cq);
        float4 zv = *(const float4*)(Zc + (size_t)(m_base + row) * L_ + cq);
        float dx = qv.x - zv.x, dy = qv.y - zv.y, dz = qv.z - zv.z, dw = qv.w - zv.w;
        sse += dx * dx + dy * dy + dz * dz + dw * dw;
    }
#pragma unroll
    for (int o = 32; o > 0; o >>= 1) sse += __shfl_down(sse, o);
    int wv = tid >> 6, ln = tid & 63;
    if (ln == 0) redbuf[wv] = sse;
    __syncthreads();
    if (tid == 0)
        ssepart[blockIdx.x] = redbuf[0] + redbuf[1] + redbuf[2] + redbuf[3];
}

// ---------------------------------------------------------------------------
__global__ __launch_bounds__(256) void finalize_kernel(
    const float* __restrict__ klpart, const float* __restrict__ ssepart,
    float* __restrict__ loss_out)
{
    float skl = 0.f, ssse = 0.f;
    for (int i = threadIdx.x; i < 2048; i += 256) { skl += klpart[i]; ssse += ssepart[i]; }
#pragma unroll
    for (int o = 32; o > 0; o >>= 1) { skl += __shfl_down(skl, o); ssse += __shfl_down(ssse, o); }
    __shared__ float s1[4], s2[4];
    int w = threadIdx.x >> 6, l = threadIdx.x & 63;
    if (l == 0) { s1[w] = skl; s2[w] = ssse; }
    __syncthreads();
    if (threadIdx.x == 0) {
        float K = s1[0] + s1[1] + s1[2] + s1[3];
        float S = s2[0] + s2[1] + s2[2] + s2[3];
        loss_out[0] = 1.25f * (S / 16777216.0f) - 0.5f * K;
    }
}

// ---------------------------------------------------------------------------
extern "C" void kernel_launch(void* const* d_in, const int* in_sizes, int n_in,
                              void* d_out, int out_size, void* d_ws, size_t ws_size,
                              hipStream_t stream)
{
    const float* traj     = (const float*)d_in[0];
    const float* eps      = (const float*)d_in[1];
    const float* enc_Wih  = (const float*)d_in[2];
    const float* enc_Whh  = (const float*)d_in[3];
    const float* enc_bih  = (const float*)d_in[4];
    const float* enc_bhh  = (const float*)d_in[5];
    const float* fc_mu_W  = (const float*)d_in[6];
    const float* fc_mu_b  = (const float*)d_in[7];
    const float* fc_lv_W  = (const float*)d_in[8];
    const float* fc_lv_b  = (const float*)d_in[9];
    const float* codebook = (const float*)d_in[10];
    const float* dec_Wih  = (const float*)d_in[11];
    const float* dec_Whh  = (const float*)d_in[12];
    const float* dec_bih  = (const float*)d_in[13];
    const float* dec_bhh  = (const float*)d_in[14];
    const float* dec_fc_W = (const float*)d_in[15];
    const float* dec_fc_b = (const float*)d_in[16];

    float* out   = (float*)d_out;
    float* recon = out;                 // [256,512,96]
    float* loss  = out + 12582912;      // scalar
    float* idxf  = out + 12582913;      // [131072]

    // pick largest chunk Tc that fits in ws_size
    int Tc = 512;
    while (Tc > 16) {
        size_t bytes = 4ull * ((size_t)B_ * Tc * (G_ + H_ + L_)
                               + 524288 + 1024 + 65536 + 4096 + 131072);
        if (bytes <= ws_size) break;
        Tc >>= 1;
    }
    const int lg = __builtin_ctz(Tc);
    const int nchunks = T_ / Tc;
    const int blocksPerChunk = (B_ * Tc) / 64;

    float* ws = (float*)d_ws;
    float* preXc   = ws;                              // B*Tc*512
    float* Hc      = preXc + (size_t)B_ * Tc * G_;    // B*Tc*128
    float* Zc      = Hc + (size_t)B_ * Tc * H_;       // B*Tc*128
    float* preCB   = Zc + (size_t)B_ * Tc * L_;       // 524288
    float* ccbuf   = preCB + (size_t)K_ * G_;         // 1024
    float* hstate  = ccbuf + 1024;                    // 32768
    float* cstate  = hstate + (size_t)B_ * H_;        // 32768
    float* klpart  = cstate + (size_t)B_ * H_;        // 2048
    float* ssepart = klpart + 2048;                   // 2048
    ushort* cbh    = (ushort*)(ssepart + 2048);       // 131072 ushort
    ushort* cbl    = cbh + (size_t)K_ * L_;           // 131072 ushort

    // preCB = codebook @ dec_Wih^T + dec_bih + dec_bhh  [1024,512]
    gemm_bias_kernel<<<dim3(8, 16), 256, 0, stream>>>(
        codebook, 0, 30, dec_Wih, dec_bih, dec_bhh, preCB, 0, 30, G_, L_);
    cc_kernel<<<4, 256, 0, stream>>>(codebook, ccbuf);
    cbsplit_kernel<<<512, 256, 0, stream>>>(codebook, cbh, cbl);
    zero_kernel<<<256, 256, 0, stream>>>(hstate, 2 * B_ * H_);

    // ---- encoder + VQ, chunked over T ----
    for (int ci = 0; ci < nchunks; ++ci) {
        const int t0 = ci * Tc;
        gemm_bias_kernel<<<dim3(8, blocksPerChunk), 256, 0, stream>>>(
            traj + (size_t)t0 * D_, (long)T_ * D_, lg,
            enc_Wih, enc_bih, enc_bhh,
            preXc, 0, 30, G_, D_);
        lstm_kernel<<<B_, 512, 0, stream>>>(
            preXc, nullptr, nullptr, enc_Whh, Hc, hstate, cstate, Tc);
        mu_logvar_z_kernel<<<blocksPerChunk, 256, 0, stream>>>(
            Hc, fc_mu_W, fc_mu_b, fc_lv_W, fc_lv_b,
            eps + (size_t)t0 * L_, (long)T_ * L_, lg,
            Zc, klpart + (size_t)ci * blocksPerChunk);
        vq_kernel<<<blocksPerChunk, 256, 0, stream>>>(
            Zc, cbh, cbl, codebook, ccbuf, idxf + t0, lg,
            ssepart + (size_t)ci * blocksPerChunk);
    }

    zero_kernel<<<256, 256, 0, stream>>>(hstate, 2 * B_ * H_);

    // ---- decoder + recon, chunked over T ----
    for (int ci = 0; ci < nchunks; ++ci) {
        const int t0 = ci * Tc;
        lstm_kernel<<<B_, 512, 0, stream>>>(
            nullptr, idxf + t0, preCB, dec_Whh, Hc, hstate, cstate, Tc);
        gemm_bias_kernel<<<dim3(2, blocksPerChunk), 256, 0, stream>>>(
            Hc, 0, 30, dec_fc_W, dec_fc_b, nullptr,
            recon + (size_t)t0 * D_, (long)T_ * D_, lg, D_, H_);
    }

    finalize_kernel<<<1, 256, 0, stream>>>(klpart, ssepart, loss);
}